// Round 1
// baseline (3867.959 us; speedup 1.0000x reference)
//
#include <hip/hip_runtime.h>
#include <math.h>

#define NN 100000
#define NE 1600000
#define NG 128
#define HD 128
#define WLK 16
#define NL 5
#define NOUT 10
#define BNEPS 1e-5f
#define CDIV(a,b) (((a)+(b)-1)/(b))

// ---------------- setup: degree histogram + node-per-graph counts ----------------
__global__ void k_deg_cnt(const int* __restrict__ col0, const int* __restrict__ batch,
                          int* __restrict__ deg, int* __restrict__ cnt) {
    int i = blockIdx.x * blockDim.x + threadIdx.x;
    int stride = gridDim.x * blockDim.x;
    for (int e = i; e < NE; e += stride) atomicAdd(&deg[col0[e]], 1);
    for (int v = i; v < NN; v += stride) atomicAdd(&cnt[batch[v]], 1);
}

// ---------------- exclusive scan over deg (3-kernel) ----------------
__global__ void k_scan1(const int* __restrict__ deg, int* __restrict__ blksum) {
    __shared__ int sm[256];
    int i = blockIdx.x * 256 + threadIdx.x;
    sm[threadIdx.x] = (i < NN) ? deg[i] : 0;
    __syncthreads();
    for (int s = 128; s > 0; s >>= 1) {
        if (threadIdx.x < s) sm[threadIdx.x] += sm[threadIdx.x + s];
        __syncthreads();
    }
    if (threadIdx.x == 0) blksum[blockIdx.x] = sm[0];
}

__global__ void k_scan2(int* __restrict__ blksum, int nblk) {
    __shared__ int sm[512];
    int t = threadIdx.x;
    int x = (t < nblk) ? blksum[t] : 0;
    sm[t] = x; __syncthreads();
    for (int s = 1; s < 512; s <<= 1) {
        int v = (t >= s) ? sm[t - s] : 0;
        __syncthreads();
        sm[t] += v;
        __syncthreads();
    }
    if (t < nblk) blksum[t] = sm[t] - x;   // exclusive
}

__global__ void k_scan3(const int* __restrict__ deg, const int* __restrict__ blksum,
                        int* __restrict__ rowptr, int* __restrict__ cursor) {
    __shared__ int sm[256];
    int t = threadIdx.x;
    int i = blockIdx.x * 256 + t;
    int x = (i < NN) ? deg[i] : 0;
    sm[t] = x; __syncthreads();
    for (int s = 1; s < 256; s <<= 1) {
        int v = (t >= s) ? sm[t - s] : 0;
        __syncthreads();
        sm[t] += v;
        __syncthreads();
    }
    int excl = blksum[blockIdx.x] + sm[t] - x;
    if (i < NN) { rowptr[i] = excl; cursor[i] = excl; }
    if (i == NN - 1) rowptr[NN] = excl + x;   // == NE
}

__global__ void k_scatter(const int* __restrict__ row0, const int* __restrict__ col0,
                          int* __restrict__ cursor, int* __restrict__ esrc) {
    int i = blockIdx.x * blockDim.x + threadIdx.x;
    int stride = gridDim.x * blockDim.x;
    for (int e = i; e < NE; e += stride) {
        int c = col0[e];
        int pos = atomicAdd(&cursor[c], 1);
        esrc[pos] = row0[e];
    }
}

// ---------------- PE init: dinv, p0 (per-graph uniform), pd0 = p0*dinv ----------------
__global__ void k_init_pe(const int* __restrict__ deg, const int* __restrict__ batch,
                          const int* __restrict__ cnt, float* __restrict__ dinv,
                          float* __restrict__ p, float* __restrict__ pd) {
    int v = blockIdx.x * 256 + threadIdx.x;
    if (v >= NN) return;
    float dv = rsqrtf((float)(deg[v] + 1));   // +1: self-loop
    dinv[v] = dv;
    float pv = 1.0f / fmaxf((float)cnt[batch[v]], 1.0f);
    p[v] = pv; pd[v] = pv * dv;
}

// one random-walk step; records rw[step]=p_in, produces p_out and pd_out=p_out*dinv
__global__ void k_rw_step(const float* __restrict__ pin, const float* __restrict__ pdin,
                          const int* __restrict__ rowptr, const int* __restrict__ esrc,
                          const float* __restrict__ dinv, float* __restrict__ rwslice,
                          float* __restrict__ pout, float* __restrict__ pdout) {
    int v = blockIdx.x * 256 + threadIdx.x;
    if (v >= NN) return;
    int b = rowptr[v], e = rowptr[v + 1];
    float s = 0.f;
    for (int i = b; i < e; ++i) s += pdin[esrc[i]];
    float dv = dinv[v];
    float pv = pin[v];
    float np = s * dv + pv * dv * dv;          // incl. self-loop term
    float nxt = 0.9f * np + 0.1f * pv;
    rwslice[v] = pv;
    pout[v] = nxt;
    pdout[v] = nxt * dv;
}

// M[s][j] = sum_w pe_w[s][w]*proj_w[128+w][j];  c1[j] = emb.proj_w[:,j] + proj_b[j] + pe_b.proj_w2[:,j]
__global__ void k_mc1(const float* __restrict__ emb, const float* __restrict__ pe_w,
                      const float* __restrict__ pe_b, const float* __restrict__ proj_w,
                      const float* __restrict__ proj_b, float* __restrict__ M,
                      float* __restrict__ c1) {
    int j = threadIdx.x;   // 0..127
    float c0 = proj_b[j];
    for (int d = 0; d < HD; ++d) c0 += emb[d] * proj_w[d * HD + j];
    for (int w = 0; w < WLK; ++w) c0 += pe_b[w] * proj_w[(HD + w) * HD + j];
    c1[j] = c0;
    for (int s = 0; s < WLK; ++s) {
        float m = 0.f;
        for (int w = 0; w < WLK; ++w) m += pe_w[s * WLK + w] * proj_w[(HD + w) * HD + j];
        M[s * HD + j] = m;
    }
}

// h[v][j] = c1[j] + sum_s rw[s][v] * M[s][j]
__global__ void k_proj(const float* __restrict__ rw, const float* __restrict__ M,
                       const float* __restrict__ c1, float* __restrict__ h) {
    int idx = blockIdx.x * 256 + threadIdx.x;
    if (idx >= NN * HD) return;
    int v = idx >> 7, j = idx & 127;
    float acc = c1[j];
#pragma unroll
    for (int s = 0; s < WLK; ++s) acc += rw[s * NN + v] * M[s * HD + j];
    h[idx] = acc;
}

// agg[v] = h[v] + sum_{e: col==v} h[src_e]   (one wave per node, float2 per lane)
__global__ void k_agg(const float* __restrict__ h, const int* __restrict__ rowptr,
                      const int* __restrict__ esrc, float* __restrict__ agg) {
    int wave = threadIdx.x >> 6;
    int lane = threadIdx.x & 63;
    int v = blockIdx.x * 4 + wave;
    if (v >= NN) return;
    const float2* h2 = (const float2*)h;
    float2 acc = h2[(size_t)v * 64 + lane];
    int b = rowptr[v], e = rowptr[v + 1];
    for (int i = b; i < e; ++i) {
        int src = esrc[i];
        float2 x = h2[(size_t)src * 64 + lane];
        acc.x += x.x; acc.y += x.y;
    }
    ((float2*)agg)[(size_t)v * 64 + lane] = acc;
}

// ---------------- fp32 GEMM: C[v][n] = op(A[v][:] @ W[:][n] + bias[n]) (+res), optional BN-stats ----------------
// tile: 128 rows x 64 cols, K tiled by 64. block=256 threads, thread = 8 rows x 4 cols.
template <int K, int NT, bool RELU, bool ADDRES, bool DOSTATS>
__global__ __launch_bounds__(256)
void k_gemm(const float* __restrict__ A, const float* __restrict__ W,
            const float* __restrict__ bias, float* __restrict__ C,
            const float* __restrict__ res, float* __restrict__ stS,
            float* __restrict__ stQ) {
    constexpr int ASTR = 132;                 // padded k-stride (16B aligned, conflict-free)
    __shared__ float As[64 * ASTR];           // A-tile transposed [k][row]
    __shared__ float Ws[64 * 64];             // W-tile [k][col]
    const int tid = threadIdx.x;
    const int rg = tid >> 4, cg = tid & 15;
    const int vr0 = blockIdx.x * 128;
    const int cb = blockIdx.y * 64;
    float acc[8][4] = {};

    for (int kt = 0; kt < K / 64; ++kt) {
        __syncthreads();
        // A tile: lanes map to consecutive rows (conflict-free LDS transpose writes)
#pragma unroll
        for (int it = 0; it < 8; ++it) {
            int f = it * 256 + tid;           // 0..2047 float4 slots
            int kg = f >> 7, row = f & 127;
            int vr = vr0 + row;
            float4 a = make_float4(0.f, 0.f, 0.f, 0.f);
            if (vr < NN) a = *(const float4*)&A[(size_t)vr * K + kt * 64 + kg * 4];
            As[(kg * 4 + 0) * ASTR + row] = a.x;
            As[(kg * 4 + 1) * ASTR + row] = a.y;
            As[(kg * 4 + 2) * ASTR + row] = a.z;
            As[(kg * 4 + 3) * ASTR + row] = a.w;
        }
        // W tile: fully coalesced global + contiguous LDS float4 writes
#pragma unroll
        for (int it = 0; it < 4; ++it) {
            int f = it * 256 + tid;           // 0..1023
            int k = f >> 4, c4 = f & 15;
            float4 w = *(const float4*)&W[(size_t)(kt * 64 + k) * NT + cb + c4 * 4];
            *(float4*)&Ws[f * 4] = w;
        }
        __syncthreads();
#pragma unroll 16
        for (int k = 0; k < 64; ++k) {
            const float4 b4 = *(const float4*)&Ws[k * 64 + cg * 4];
            const float4 a0 = *(const float4*)&As[k * ASTR + rg * 8];
            const float4 a1 = *(const float4*)&As[k * ASTR + rg * 8 + 4];
            const float av[8] = {a0.x, a0.y, a0.z, a0.w, a1.x, a1.y, a1.z, a1.w};
            const float bv[4] = {b4.x, b4.y, b4.z, b4.w};
#pragma unroll
            for (int i2 = 0; i2 < 8; ++i2)
#pragma unroll
                for (int j = 0; j < 4; ++j)
                    acc[i2][j] = fmaf(av[i2], bv[j], acc[i2][j]);
        }
    }

    const float4 b4 = *(const float4*)&bias[cb + cg * 4];
    const float bb[4] = {b4.x, b4.y, b4.z, b4.w};
    float ssum[4] = {0, 0, 0, 0}, sq[4] = {0, 0, 0, 0};
#pragma unroll
    for (int i2 = 0; i2 < 8; ++i2) {
        int vr = vr0 + rg * 8 + i2;
        if (vr < NN) {
            float out[4];
            float4 r4 = make_float4(0.f, 0.f, 0.f, 0.f);
            if (ADDRES) r4 = *(const float4*)&res[(size_t)vr * NT + cb + cg * 4];
            const float rv[4] = {r4.x, r4.y, r4.z, r4.w};
#pragma unroll
            for (int j = 0; j < 4; ++j) {
                float x = acc[i2][j] + bb[j];
                if (RELU) x = fmaxf(x, 0.f);
                if (ADDRES) x += rv[j];
                out[j] = x;
                if (DOSTATS) { ssum[j] += x; sq[j] += x * x; }
            }
            *(float4*)&C[(size_t)vr * NT + cb + cg * 4] =
                make_float4(out[0], out[1], out[2], out[3]);
        }
    }
    if (DOSTATS) {
        __syncthreads();                       // all LDS reads of As done
#pragma unroll
        for (int j = 0; j < 4; ++j) {
            As[(cg * 4 + j) * 16 + rg] = ssum[j];
            As[1024 + (cg * 4 + j) * 16 + rg] = sq[j];
        }
        __syncthreads();
        if (tid < 64) {
            float s = 0.f, q = 0.f;
#pragma unroll
            for (int r = 0; r < 16; ++r) {
                s += As[tid * 16 + r];
                q += As[1024 + tid * 16 + r];
            }
            atomicAdd(&stS[cb + tid], s);
            atomicAdd(&stQ[cb + tid], q);
        }
    }
}

// GIN post: h += relu(bn(z))
__global__ void k_bn_relu_res(const float* __restrict__ z, const float* __restrict__ stS,
                              const float* __restrict__ stQ, const float* __restrict__ g,
                              const float* __restrict__ b, float* __restrict__ h) {
    int idx = blockIdx.x * 256 + threadIdx.x;
    if (idx >= NN * HD) return;
    int c = idx & 127;
    float mu = stS[c] * (1.0f / NN);
    float var = stQ[c] * (1.0f / NN) - mu * mu;
    float inv = rsqrtf(var + BNEPS);
    float x = (z[idx] - mu) * inv * g[c] + b[c];
    h[idx] += fmaxf(x, 0.f);
}

// FFN post: h = bn(t)
__global__ void k_bn(const float* __restrict__ t, const float* __restrict__ stS,
                     const float* __restrict__ stQ, const float* __restrict__ g,
                     const float* __restrict__ b, float* __restrict__ h) {
    int idx = blockIdx.x * 256 + threadIdx.x;
    if (idx >= NN * HD) return;
    int c = idx & 127;
    float mu = stS[c] * (1.0f / NN);
    float var = stQ[c] * (1.0f / NN) - mu * mu;
    float inv = rsqrtf(var + BNEPS);
    h[idx] = (t[idx] - mu) * inv * g[c] + b[c];
}

// segment-sum pooling; batch is sorted, so run-accumulate then flush one atomic per run
__global__ void k_pool(const float* __restrict__ h, const int* __restrict__ batch,
                       float* __restrict__ gsum) {
    int c = threadIdx.x;                       // 128 channels
    int v0 = blockIdx.x * 256;
    if (v0 >= NN) return;
    int vend = (v0 + 256 < NN) ? v0 + 256 : NN;
    float acc = 0.f;
    int bprev = batch[v0];
    for (int v = v0; v < vend; ++v) {
        int bb = batch[v];
        if (bb != bprev) {
            atomicAdd(&gsum[bprev * HD + c], acc);
            acc = 0.f; bprev = bb;
        }
        acc += h[(size_t)v * HD + c];
    }
    atomicAdd(&gsum[bprev * HD + c], acc);
}

// head: out = relu(g@w1+b1)@w2+b2, one block per graph
__global__ void k_head(const float* __restrict__ gsum, const int* __restrict__ cnt,
                       const float* __restrict__ w1, const float* __restrict__ b1,
                       const float* __restrict__ w2, const float* __restrict__ b2,
                       float* __restrict__ out) {
    __shared__ float gv[HD], av[HD];
    int gid = blockIdx.x, t = threadIdx.x;
    float c = fmaxf((float)cnt[gid], 1.0f);
    gv[t] = gsum[gid * HD + t] / c;
    __syncthreads();
    float a = b1[t];
    for (int k = 0; k < HD; ++k) a += gv[k] * w1[k * HD + t];
    av[t] = fmaxf(a, 0.f);
    __syncthreads();
    if (t < NOUT) {
        float o = b2[t];
        for (int k = 0; k < HD; ++k) o += av[k] * w2[k * NOUT + t];
        out[gid * NOUT + t] = o;
    }
}

// ---------------- workspace layout (bytes) ----------------
#define SZF 4ULL
static constexpr size_t OFF_H      = 0;
static constexpr size_t SZ_H       = (size_t)NN * HD * SZF;          // 51.2 MB
static constexpr size_t OFF_BUFA   = OFF_H + SZ_H;
static constexpr size_t SZ_BUFA    = (size_t)NN * 256 * SZF;         // 102.4 MB
static constexpr size_t OFF_BUFB   = OFF_BUFA + SZ_BUFA;
static constexpr size_t OFF_RW     = OFF_BUFB + SZ_H;
static constexpr size_t OFF_P0     = OFF_RW + (size_t)WLK * NN * SZF;
static constexpr size_t OFF_P1     = OFF_P0 + (size_t)NN * SZF;
static constexpr size_t OFF_PD0    = OFF_P1 + (size_t)NN * SZF;
static constexpr size_t OFF_PD1    = OFF_PD0 + (size_t)NN * SZF;
static constexpr size_t OFF_DINV   = OFF_PD1 + (size_t)NN * SZF;
static constexpr size_t OFF_ESRC   = OFF_DINV + (size_t)NN * SZF;
static constexpr size_t OFF_ROWPTR = OFF_ESRC + (size_t)NE * 4;
static constexpr size_t OFF_CURSOR = OFF_ROWPTR + 400016;            // (NN+1)*4 padded to 16B
static constexpr size_t OFF_BLK    = OFF_CURSOR + (size_t)NN * 4;
static constexpr size_t OFF_M      = OFF_BLK + 512 * 4;
static constexpr size_t OFF_C1     = OFF_M + (size_t)WLK * HD * SZF;
// zero arena (single memset): deg | cnt | stats(10x2x128) | gsum
static constexpr size_t OFF_DEG    = OFF_C1 + (size_t)HD * SZF;
static constexpr size_t OFF_CNT    = OFF_DEG + (size_t)NN * 4;
static constexpr size_t OFF_STATS  = OFF_CNT + (size_t)NG * 4;
static constexpr size_t OFF_GSUM   = OFF_STATS + 10 * 2 * HD * SZF;
static constexpr size_t ZERO_BYTES = (size_t)NN * 4 + NG * 4 + 10 * 2 * HD * SZF + (size_t)NG * HD * SZF;

extern "C" void kernel_launch(void* const* d_in, const int* in_sizes, int n_in,
                              void* d_out, int out_size, void* d_ws, size_t ws_size,
                              hipStream_t stream) {
    const int* eidx = (const int*)d_in[1];
    const int* row0 = eidx;
    const int* col0 = eidx + NE;
    const int* batch = (const int*)d_in[2];
    const float* emb = (const float*)d_in[3];
    const float* pe_w = (const float*)d_in[4];
    const float* pe_b = (const float*)d_in[5];
    const float* proj_w = (const float*)d_in[6];
    const float* proj_b = (const float*)d_in[7];
    const float* gin_w1 = (const float*)d_in[8];
    const float* gin_b1 = (const float*)d_in[9];
    const float* gin_w2 = (const float*)d_in[10];
    const float* gin_b2 = (const float*)d_in[11];
    const float* bn_g = (const float*)d_in[12];
    const float* bn_b = (const float*)d_in[13];
    const float* ffn_w1 = (const float*)d_in[14];
    const float* ffn_b1 = (const float*)d_in[15];
    const float* ffn_w2 = (const float*)d_in[16];
    const float* ffn_b2 = (const float*)d_in[17];
    const float* ffn_bn_g = (const float*)d_in[18];
    const float* ffn_bn_b = (const float*)d_in[19];
    const float* out_w1 = (const float*)d_in[20];
    const float* out_b1 = (const float*)d_in[21];
    const float* out_w2 = (const float*)d_in[22];
    const float* out_b2 = (const float*)d_in[23];
    float* out = (float*)d_out;

    char* ws = (char*)d_ws;
    float* h    = (float*)(ws + OFF_H);
    float* bufA = (float*)(ws + OFF_BUFA);           // agg / f1
    float* z1   = bufA + (size_t)NN * HD;            // second half of bufA
    float* bufB = (float*)(ws + OFF_BUFB);           // z2 / f2(+res)
    float* rw   = (float*)(ws + OFF_RW);
    float* p0   = (float*)(ws + OFF_P0);
    float* p1   = (float*)(ws + OFF_P1);
    float* pd0  = (float*)(ws + OFF_PD0);
    float* pd1  = (float*)(ws + OFF_PD1);
    float* dinv = (float*)(ws + OFF_DINV);
    int* esrc   = (int*)(ws + OFF_ESRC);
    int* rowptr = (int*)(ws + OFF_ROWPTR);
    int* cursor = (int*)(ws + OFF_CURSOR);
    int* blksum = (int*)(ws + OFF_BLK);
    float* M    = (float*)(ws + OFF_M);
    float* c1   = (float*)(ws + OFF_C1);
    int* deg    = (int*)(ws + OFF_DEG);
    int* cnt    = (int*)(ws + OFF_CNT);
    float* stats = (float*)(ws + OFF_STATS);
    float* gsum = (float*)(ws + OFF_GSUM);

    const int NB = CDIV(NN, 256);   // 391

    hipMemsetAsync(ws + OFF_DEG, 0, ZERO_BYTES, stream);

    k_deg_cnt<<<2048, 256, 0, stream>>>(col0, batch, deg, cnt);
    k_scan1<<<NB, 256, 0, stream>>>(deg, blksum);
    k_scan2<<<1, 512, 0, stream>>>(blksum, NB);
    k_scan3<<<NB, 256, 0, stream>>>(deg, blksum, rowptr, cursor);
    k_scatter<<<2048, 256, 0, stream>>>(row0, col0, cursor, esrc);
    k_init_pe<<<NB, 256, 0, stream>>>(deg, batch, cnt, dinv, p0, pd0);
    k_mc1<<<1, 128, 0, stream>>>(emb, pe_w, pe_b, proj_w, proj_b, M, c1);

    for (int s = 0; s < WLK; ++s) {
        const float* pin = (s & 1) ? p1 : p0;
        const float* pdin = (s & 1) ? pd1 : pd0;
        float* pout = (s & 1) ? p0 : p1;
        float* pdout = (s & 1) ? pd0 : pd1;
        k_rw_step<<<NB, 256, 0, stream>>>(pin, pdin, rowptr, esrc, dinv,
                                          rw + (size_t)s * NN, pout, pdout);
    }
    k_proj<<<CDIV(NN * HD, 256), 256, 0, stream>>>(rw, M, c1, h);

    dim3 g128(CDIV(NN, 128), 2);   // NT=128
    dim3 g256(CDIV(NN, 128), 4);   // NT=256
    for (int i = 0; i < NL; ++i) {
        float* stGin = stats + (size_t)(2 * i) * 256;
        float* stFfn = stats + (size_t)(2 * i + 1) * 256;
        k_agg<<<CDIV(NN, 4), 256, 0, stream>>>(h, rowptr, esrc, bufA);
        k_gemm<128, 128, true, false, false><<<g128, 256, 0, stream>>>(
            bufA, gin_w1 + (size_t)i * HD * HD, gin_b1 + i * HD, z1, nullptr, nullptr, nullptr);
        k_gemm<128, 128, false, false, true><<<g128, 256, 0, stream>>>(
            z1, gin_w2 + (size_t)i * HD * HD, gin_b2 + i * HD, bufB, nullptr, stGin, stGin + 128);
        k_bn_relu_res<<<CDIV(NN * HD, 256), 256, 0, stream>>>(
            bufB, stGin, stGin + 128, bn_g + i * HD, bn_b + i * HD, h);
        k_gemm<128, 256, true, false, false><<<g256, 256, 0, stream>>>(
            h, ffn_w1 + (size_t)i * HD * 256, ffn_b1 + i * 256, bufA, nullptr, nullptr, nullptr);
        k_gemm<256, 128, false, true, true><<<g128, 256, 0, stream>>>(
            bufA, ffn_w2 + (size_t)i * 256 * HD, ffn_b2 + i * HD, bufB, h, stFfn, stFfn + 128);
        k_bn<<<CDIV(NN * HD, 256), 256, 0, stream>>>(
            bufB, stFfn, stFfn + 128, ffn_bn_g + i * HD, ffn_bn_b + i * HD, h);
    }

    k_pool<<<NB, 128, 0, stream>>>(h, batch, gsum);
    k_head<<<NG, 128, 0, stream>>>(gsum, cnt, out_w1, out_b1, out_w2, out_b2, out);
}

// Round 3
// 2213.776 us; speedup vs baseline: 1.7472x; 1.7472x over previous
//
#include <hip/hip_runtime.h>
#include <math.h>

#define NN 100000
#define NE 1600000
#define NG 128
#define HD 128
#define WLK 16
#define NL 5
#define NOUT 10
#define BNEPS 1e-5f
#define CDIV(a,b) (((a)+(b)-1)/(b))

#define NBKT 782          // buckets of 128 nodes (col>>7)
#define NEB 400           // edge-blocks for bucketing
#define EPB 4000          // edges per edge-block (NEB*EPB == NE)
#define NSCAN (NBKT*NEB)  // 312800
#define NSB CDIV(NSCAN,1024)  // 306
#define NBM 782           // GEMM row-blocks (CDIV(NN,128))

typedef float f32x4 __attribute__((ext_vector_type(4)));
typedef _Float16 f16x8 __attribute__((ext_vector_type(8)));
typedef unsigned short ushort_t;
typedef unsigned int uint_t;

__device__ __forceinline__ ushort_t f2h(float x) {
    union { _Float16 h; ushort_t u; } c;
    c.h = (_Float16)x;                     // v_cvt_f16_f32, RNE
    return c.u;
}
__device__ __forceinline__ float h2f(ushort_t u) {
    union { ushort_t u; _Float16 h; } c;
    c.u = u;
    return (float)c.h;
}

// ---------------- graph-size counts via binary search (batch is sorted) ----------------
__global__ void k_cnt(const int* __restrict__ batch, int* __restrict__ cnt) {
    int g = threadIdx.x;
    if (g >= NG) return;
    int lo0 = 0, hi0 = NN;
    while (lo0 < hi0) { int m = (lo0 + hi0) >> 1; if (batch[m] < g) lo0 = m + 1; else hi0 = m; }
    int lo1 = lo0, hi1 = NN;
    while (lo1 < hi1) { int m = (lo1 + hi1) >> 1; if (batch[m] < g + 1) lo1 = m + 1; else hi1 = m; }
    cnt[g] = lo1 - lo0;
}

// ---------------- atomic-free CSR build: bucket histogram ----------------
__global__ void k_bhist(const int* __restrict__ col0, int* __restrict__ bhist) {
    __shared__ int hist[NBKT];
    for (int i = threadIdx.x; i < NBKT; i += 256) hist[i] = 0;
    __syncthreads();
    int e0 = blockIdx.x * EPB;
    for (int e = e0 + threadIdx.x; e < e0 + EPB; e += 256) atomicAdd(&hist[col0[e] >> 7], 1);
    __syncthreads();
    for (int i = threadIdx.x; i < NBKT; i += 256) bhist[i * NEB + blockIdx.x] = hist[i];
}

// generic exclusive scan over NSCAN ints: chunk-reduce, chunk-sum scan, chunk-scan
__global__ void k_gscan1(const int* __restrict__ in, int* __restrict__ bsum) {
    __shared__ int sm[256];
    int base = blockIdx.x * 1024 + threadIdx.x * 4;
    int s = 0;
#pragma unroll
    for (int i = 0; i < 4; ++i) { int e = base + i; if (e < NSCAN) s += in[e]; }
    sm[threadIdx.x] = s; __syncthreads();
    for (int st = 128; st > 0; st >>= 1) {
        if (threadIdx.x < st) sm[threadIdx.x] += sm[threadIdx.x + st];
        __syncthreads();
    }
    if (threadIdx.x == 0) bsum[blockIdx.x] = sm[0];
}

__global__ void k_scan2(int* __restrict__ blksum, int nblk) {
    __shared__ int sm[512];
    int t = threadIdx.x;
    int x = (t < nblk) ? blksum[t] : 0;
    sm[t] = x; __syncthreads();
    for (int s = 1; s < 512; s <<= 1) {
        int v = (t >= s) ? sm[t - s] : 0;
        __syncthreads();
        sm[t] += v;
        __syncthreads();
    }
    if (t < nblk) blksum[t] = sm[t] - x;   // exclusive
}

__global__ void k_gscan3(const int* __restrict__ in, const int* __restrict__ bsum,
                         int* __restrict__ out) {
    __shared__ int sm[256];
    int t = threadIdx.x;
    int base = blockIdx.x * 1024 + t * 4;
    int v[4]; int s = 0;
#pragma unroll
    for (int i = 0; i < 4; ++i) { int e = base + i; v[i] = (e < NSCAN) ? in[e] : 0; s += v[i]; }
    sm[t] = s; __syncthreads();
    for (int st = 1; st < 256; st <<= 1) {
        int x = (t >= st) ? sm[t - st] : 0;
        __syncthreads();
        sm[t] += x;
        __syncthreads();
    }
    int excl = sm[t] - s + bsum[blockIdx.x];
#pragma unroll
    for (int i = 0; i < 4; ++i) { int e = base + i; if (e < NSCAN) { out[e] = excl; excl += v[i]; } }
}

__global__ void k_escatter(const int* __restrict__ row0, const int* __restrict__ col0,
                           const int* __restrict__ boffs, int2* __restrict__ epair) {
    __shared__ int cur[NBKT];
    for (int i = threadIdx.x; i < NBKT; i += 256) cur[i] = boffs[i * NEB + blockIdx.x];
    __syncthreads();
    int e0 = blockIdx.x * EPB;
    for (int e = e0 + threadIdx.x; e < e0 + EPB; e += 256) {
        int c = col0[e], r = row0[e];
        int pos = atomicAdd(&cur[c >> 7], 1);
        epair[pos] = make_int2(c, r);
    }
}

__global__ void k_bucket(const int2* __restrict__ epair, const int* __restrict__ boffs,
                         int* __restrict__ rowptr, int* __restrict__ deg,
                         int* __restrict__ esrc) {
    __shared__ int cnt_[128], scn[128], cur_[128];
    int bkt = blockIdx.x, t = threadIdx.x;
    int bs = boffs[bkt * NEB];
    int be = (bkt + 1 < NBKT) ? boffs[(bkt + 1) * NEB] : NE;
    if (t < 128) cnt_[t] = 0;
    __syncthreads();
    for (int e = bs + t; e < be; e += 256) atomicAdd(&cnt_[epair[e].x & 127], 1);
    __syncthreads();
    int c = (t < 128) ? cnt_[t] : 0;
    if (t < 128) scn[t] = c;
    __syncthreads();
    for (int st = 1; st < 128; st <<= 1) {
        int x = (t >= st && t < 128) ? scn[t - st] : 0;
        __syncthreads();
        if (t < 128) scn[t] += x;
        __syncthreads();
    }
    if (t < 128) {
        int excl = scn[t] - c;
        int node = bkt * 128 + t;
        if (node < NN) { rowptr[node] = bs + excl; deg[node] = c; }
        cur_[t] = bs + excl;
    }
    if (bkt == NBKT - 1 && t == 0) rowptr[NN] = NE;
    __syncthreads();
    for (int e = bs + t; e < be; e += 256) {
        int2 p = epair[e];
        int pos = atomicAdd(&cur_[p.x & 127], 1);
        esrc[pos] = p.y;
    }
}

// ---------------- PE init ----------------
__global__ void k_init_pe(const int* __restrict__ deg, const int* __restrict__ batch,
                          const int* __restrict__ cnt, float* __restrict__ dinv,
                          float* __restrict__ p, float* __restrict__ pd) {
    int v = blockIdx.x * 256 + threadIdx.x;
    if (v >= NN) return;
    float dv = rsqrtf((float)(deg[v] + 1));   // +1: self-loop
    dinv[v] = dv;
    float pv = 1.0f / fmaxf((float)cnt[batch[v]], 1.0f);
    p[v] = pv; pd[v] = pv * dv;
}

__global__ void k_rw_step(const float* __restrict__ pin, const float* __restrict__ pdin,
                          const int* __restrict__ rowptr, const int* __restrict__ esrc,
                          const float* __restrict__ dinv, float* __restrict__ rwslice,
                          float* __restrict__ pout, float* __restrict__ pdout) {
    int v = blockIdx.x * 256 + threadIdx.x;
    if (v >= NN) return;
    int b = rowptr[v], e = rowptr[v + 1];
    float s = 0.f;
    for (int i = b; i < e; ++i) s += pdin[esrc[i]];
    float dv = dinv[v];
    float pv = pin[v];
    float np = s * dv + pv * dv * dv;
    float nxt = 0.9f * np + 0.1f * pv;
    rwslice[v] = pv;
    pout[v] = nxt;
    pdout[v] = nxt * dv;
}

__global__ void k_mc1(const float* __restrict__ emb, const float* __restrict__ pe_w,
                      const float* __restrict__ pe_b, const float* __restrict__ proj_w,
                      const float* __restrict__ proj_b, float* __restrict__ M,
                      float* __restrict__ c1) {
    int j = threadIdx.x;
    float c0 = proj_b[j];
    for (int d = 0; d < HD; ++d) c0 += emb[d] * proj_w[d * HD + j];
    for (int w = 0; w < WLK; ++w) c0 += pe_b[w] * proj_w[(HD + w) * HD + j];
    c1[j] = c0;
    for (int s = 0; s < WLK; ++s) {
        float m = 0.f;
        for (int w = 0; w < WLK; ++w) m += pe_w[s * WLK + w] * proj_w[(HD + w) * HD + j];
        M[s * HD + j] = m;
    }
}

__global__ void k_proj(const float* __restrict__ rw, const float* __restrict__ M,
                       const float* __restrict__ c1, float* __restrict__ h,
                       ushort_t* __restrict__ hb) {
    int idx = blockIdx.x * 256 + threadIdx.x;
    if (idx >= NN * HD) return;
    int v = idx >> 7, j = idx & 127;
    float acc = c1[j];
#pragma unroll
    for (int s = 0; s < WLK; ++s) acc += rw[s * NN + v] * M[s * HD + j];
    h[idx] = acc;
    hb[idx] = f2h(acc);
}

// cast + transpose all GEMM weights to fp16 [n][k] once per call
__global__ void k_prepw(const float* __restrict__ g1, const float* __restrict__ g2,
                        const float* __restrict__ f1, const float* __restrict__ f2,
                        ushort_t* __restrict__ wt1, ushort_t* __restrict__ wt2,
                        ushort_t* __restrict__ wt3, ushort_t* __restrict__ wt4) {
    int i = blockIdx.x * 256 + threadIdx.x;   // 491520 total
    if (i < 81920) {
        int l = i >> 14, rem = i & 16383, n = rem >> 7, k = rem & 127;
        wt1[i] = f2h(g1[l * 16384 + k * 128 + n]);
    } else if (i < 163840) {
        int j = i - 81920;
        int l = j >> 14, rem = j & 16383, n = rem >> 7, k = rem & 127;
        wt2[j] = f2h(g2[l * 16384 + k * 128 + n]);
    } else if (i < 327680) {
        int j = i - 163840;
        int l = j >> 15, rem = j & 32767, n = rem >> 7, k = rem & 127;
        wt3[j] = f2h(f1[l * 32768 + k * 256 + n]);
    } else {
        int j = i - 327680;
        int l = j >> 15, rem = j & 32767, n = rem >> 8, k = rem & 255;
        wt4[j] = f2h(f2[l * 32768 + k * 128 + n]);
    }
}

// agg[v] = h[v] + sum_j h[src_j]  in fp16 (one wave per node, 2 ch/lane, fp32 accumulate)
__global__ void k_aggb(const uint_t* __restrict__ hb2, const int* __restrict__ rowptr,
                       const int* __restrict__ esrc, uint_t* __restrict__ aggb2) {
    int wave = threadIdx.x >> 6, lane = threadIdx.x & 63;
    int v = blockIdx.x * 4 + wave;
    if (v >= NN) return;
    uint_t u = hb2[(size_t)v * 64 + lane];
    float sx = h2f((ushort_t)(u & 0xFFFFu)), sy = h2f((ushort_t)(u >> 16));
    int b = rowptr[v], e = rowptr[v + 1];
    for (int i = b; i < e; ++i) {
        uint_t x = hb2[(size_t)esrc[i] * 64 + lane];
        sx += h2f((ushort_t)(x & 0xFFFFu));
        sy += h2f((ushort_t)(x >> 16));
    }
    aggb2[(size_t)v * 64 + lane] = (uint_t)f2h(sx) | ((uint_t)f2h(sy) << 16);
}

// ---------------- fp16 MFMA GEMM: 128x128 tile, 4 waves x (4x4) 16x16x32 frags ----------------
template <int K, bool RELU, bool OUTH16, bool ADDRES, bool DOSTATS>
__global__ __launch_bounds__(256, 2)
void k_mgemm(const ushort_t* __restrict__ A, const ushort_t* __restrict__ WT,
             const float* __restrict__ bias, ushort_t* __restrict__ Ch,
             float* __restrict__ Cf, const float* __restrict__ res,
             float* __restrict__ partS, float* __restrict__ partQ, int ncols) {
    constexpr int LDK = 72;                        // 144B row stride: 16B aligned, spread banks
    __shared__ ushort_t As[128 * LDK];
    __shared__ ushort_t Ws[128 * LDK];
    __shared__ float sS[128], sQ[128];
    const int tid = threadIdx.x;
    const int w = tid >> 6, l = tid & 63;
    const int lm = l & 15, lq = l >> 4;
    const int rb = (w >> 1) * 64, cbw = (w & 1) * 64;
    const int vr0 = blockIdx.x * 128;
    const int cb = blockIdx.y * 128;
    f32x4 acc[4][4] = {};

    for (int kt = 0; kt < K / 64; ++kt) {
        __syncthreads();
#pragma unroll
        for (int it = 0; it < 4; ++it) {
            int f = it * 256 + tid;                // 1024 16B slots per operand
            int row = f >> 3, sl = f & 7;
            uint4 a = make_uint4(0, 0, 0, 0);
            int vr = vr0 + row;
            if (vr < NN) a = *(const uint4*)&A[(size_t)vr * K + kt * 64 + sl * 8];
            *(uint4*)&As[row * LDK + sl * 8] = a;
            uint4 wv = *(const uint4*)&WT[(size_t)(cb + row) * K + kt * 64 + sl * 8];
            *(uint4*)&Ws[row * LDK + sl * 8] = wv;
        }
        __syncthreads();
#pragma unroll
        for (int kk = 0; kk < 64; kk += 32) {
            f16x8 af[4], bf[4];
#pragma unroll
            for (int i = 0; i < 4; ++i)
                af[i] = *(const f16x8*)&As[(rb + i * 16 + lm) * LDK + kk + lq * 8];
#pragma unroll
            for (int j = 0; j < 4; ++j)
                bf[j] = *(const f16x8*)&Ws[(cbw + j * 16 + lm) * LDK + kk + lq * 8];
#pragma unroll
            for (int i = 0; i < 4; ++i)
#pragma unroll
                for (int j = 0; j < 4; ++j)
                    acc[i][j] = __builtin_amdgcn_mfma_f32_16x16x32_f16(af[i], bf[j], acc[i][j], 0, 0, 0);
        }
    }

    float bcol[4];
#pragma unroll
    for (int j = 0; j < 4; ++j) bcol[j] = bias[cb + cbw + j * 16 + lm];
    if (DOSTATS && tid < 128) { sS[tid] = 0.f; sQ[tid] = 0.f; }
    __syncthreads();
    float ls[4] = {0, 0, 0, 0}, lsq[4] = {0, 0, 0, 0};
#pragma unroll
    for (int i = 0; i < 4; ++i) {
#pragma unroll
        for (int r = 0; r < 4; ++r) {
            int vr = vr0 + rb + i * 16 + lq * 4 + r;   // D row = quad*4 + reg
            if (vr < NN) {
#pragma unroll
                for (int j = 0; j < 4; ++j) {
                    float x = acc[i][j][r] + bcol[j];
                    if (RELU) x = fmaxf(x, 0.f);
                    int c = cb + cbw + j * 16 + lm;    // D col = lane&15
                    if (ADDRES) x += res[(size_t)vr * ncols + c];
                    if (DOSTATS) { ls[j] += x; lsq[j] += x * x; }
                    if (OUTH16) Ch[(size_t)vr * ncols + c] = f2h(x);
                    else        Cf[(size_t)vr * ncols + c] = x;
                }
            }
        }
    }
    if (DOSTATS) {
#pragma unroll
        for (int j = 0; j < 4; ++j) {
            atomicAdd(&sS[cbw + j * 16 + lm], ls[j]);
            atomicAdd(&sQ[cbw + j * 16 + lm], lsq[j]);
        }
        __syncthreads();
        if (tid < 128) {
            partS[(size_t)(cb + tid) * NBM + blockIdx.x] = sS[tid];
            partQ[(size_t)(cb + tid) * NBM + blockIdx.x] = sQ[tid];
        }
    }
}

__global__ void k_redstats(const float* __restrict__ partS, const float* __restrict__ partQ,
                           float* __restrict__ stS, float* __restrict__ stQ) {
    __shared__ float sm[256];
    int b = blockIdx.x;
    int which = b >> 7, c = b & 127;
    const float* src = (which ? partQ : partS) + (size_t)c * NBM;
    float s = 0.f;
    for (int i = threadIdx.x; i < NBM; i += 256) s += src[i];
    sm[threadIdx.x] = s; __syncthreads();
    for (int st = 128; st > 0; st >>= 1) {
        if (threadIdx.x < st) sm[threadIdx.x] += sm[threadIdx.x + st];
        __syncthreads();
    }
    if (threadIdx.x == 0) { if (which) stQ[c] = sm[0]; else stS[c] = sm[0]; }
}

// GIN post: h += relu(bn(z));  also refresh fp16 mirror
__global__ void k_bn_relu_res(const float* __restrict__ z, const float* __restrict__ stS,
                              const float* __restrict__ stQ, const float* __restrict__ g,
                              const float* __restrict__ b, float* __restrict__ h,
                              ushort_t* __restrict__ hb) {
    int idx = blockIdx.x * 256 + threadIdx.x;
    if (idx >= NN * HD) return;
    int c = idx & 127;
    float mu = stS[c] * (1.0f / NN);
    float var = stQ[c] * (1.0f / NN) - mu * mu;
    float inv = rsqrtf(var + BNEPS);
    float x = (z[idx] - mu) * inv * g[c] + b[c];
    float nh = h[idx] + fmaxf(x, 0.f);
    h[idx] = nh;
    hb[idx] = f2h(nh);
}

// FFN post: h = bn(t);  also refresh fp16 mirror
__global__ void k_bn(const float* __restrict__ t, const float* __restrict__ stS,
                     const float* __restrict__ stQ, const float* __restrict__ g,
                     const float* __restrict__ b, float* __restrict__ h,
                     ushort_t* __restrict__ hb) {
    int idx = blockIdx.x * 256 + threadIdx.x;
    if (idx >= NN * HD) return;
    int c = idx & 127;
    float mu = stS[c] * (1.0f / NN);
    float var = stQ[c] * (1.0f / NN) - mu * mu;
    float inv = rsqrtf(var + BNEPS);
    float nh = (t[idx] - mu) * inv * g[c] + b[c];
    h[idx] = nh;
    hb[idx] = f2h(nh);
}

__global__ void k_pool(const float* __restrict__ h, const int* __restrict__ batch,
                       float* __restrict__ gsum) {
    int c = threadIdx.x;
    int v0 = blockIdx.x * 256;
    if (v0 >= NN) return;
    int vend = (v0 + 256 < NN) ? v0 + 256 : NN;
    float acc = 0.f;
    int bprev = batch[v0];
    for (int v = v0; v < vend; ++v) {
        int bb = batch[v];
        if (bb != bprev) {
            atomicAdd(&gsum[bprev * HD + c], acc);
            acc = 0.f; bprev = bb;
        }
        acc += h[(size_t)v * HD + c];
    }
    atomicAdd(&gsum[bprev * HD + c], acc);
}

__global__ void k_head(const float* __restrict__ gsum, const int* __restrict__ cnt,
                       const float* __restrict__ w1, const float* __restrict__ b1,
                       const float* __restrict__ w2, const float* __restrict__ b2,
                       float* __restrict__ out) {
    __shared__ float gv[HD], av[HD];
    int gid = blockIdx.x, t = threadIdx.x;
    float c = fmaxf((float)cnt[gid], 1.0f);
    gv[t] = gsum[gid * HD + t] / c;
    __syncthreads();
    float a = b1[t];
    for (int k = 0; k < HD; ++k) a += gv[k] * w1[k * HD + t];
    av[t] = fmaxf(a, 0.f);
    __syncthreads();
    if (t < NOUT) {
        float o = b2[t];
        for (int k = 0; k < HD; ++k) o += av[k] * w2[k * NOUT + t];
        out[gid * NOUT + t] = o;
    }
}

// ---------------- workspace layout ----------------
static constexpr size_t AL(size_t x) { return (x + 511) & ~(size_t)511; }
static constexpr size_t OFF_H      = 0;
static constexpr size_t OFF_HB     = OFF_H      + AL((size_t)NN * HD * 4);      // fp32 h
static constexpr size_t OFF_BUFF   = OFF_HB     + AL((size_t)NN * HD * 2);      // fp16 mirror
static constexpr size_t OFF_SHARE  = OFF_BUFF   + AL((size_t)NN * HD * 4);      // z2/t fp32
static constexpr size_t SZ_SHARE   = AL((size_t)NN * 256 * 2);                  // f1h | aggh+z1h | epair
static constexpr size_t OFF_RW     = OFF_SHARE  + SZ_SHARE;
static constexpr size_t OFF_P0     = OFF_RW     + AL((size_t)WLK * NN * 4);
static constexpr size_t OFF_P1     = OFF_P0     + AL((size_t)NN * 4);
static constexpr size_t OFF_PD0    = OFF_P1     + AL((size_t)NN * 4);
static constexpr size_t OFF_PD1    = OFF_PD0    + AL((size_t)NN * 4);
static constexpr size_t OFF_DINV   = OFF_PD1    + AL((size_t)NN * 4);
static constexpr size_t OFF_ESRC   = OFF_DINV   + AL((size_t)NN * 4);
static constexpr size_t OFF_ROWPTR = OFF_ESRC   + AL((size_t)NE * 4);
static constexpr size_t OFF_DEG    = OFF_ROWPTR + AL((size_t)(NN + 1) * 4);
static constexpr size_t OFF_BHIST  = OFF_DEG    + AL((size_t)NN * 4);
static constexpr size_t OFF_BOFFS  = OFF_BHIST  + AL((size_t)NSCAN * 4);
static constexpr size_t OFF_BSUM   = OFF_BOFFS  + AL((size_t)NSCAN * 4);
static constexpr size_t OFF_WT1    = OFF_BSUM   + AL(512 * 4);
static constexpr size_t OFF_WT2    = OFF_WT1    + AL((size_t)5 * 16384 * 2);
static constexpr size_t OFF_WT3    = OFF_WT2    + AL((size_t)5 * 16384 * 2);
static constexpr size_t OFF_WT4    = OFF_WT3    + AL((size_t)5 * 32768 * 2);
static constexpr size_t OFF_PARTS  = OFF_WT4    + AL((size_t)5 * 32768 * 2);
static constexpr size_t OFF_PARTQ  = OFF_PARTS  + AL((size_t)128 * NBM * 4);
static constexpr size_t OFF_STS    = OFF_PARTQ  + AL((size_t)128 * NBM * 4);
static constexpr size_t OFF_STQ    = OFF_STS    + AL(128 * 4);
static constexpr size_t OFF_M      = OFF_STQ    + AL(128 * 4);
static constexpr size_t OFF_C1     = OFF_M      + AL((size_t)WLK * HD * 4);
static constexpr size_t OFF_CNT    = OFF_C1     + AL(HD * 4);
static constexpr size_t OFF_GSUM   = OFF_CNT    + AL(NG * 4);
static constexpr size_t ZERO_BYTES = (size_t)NG * HD * 4;                        // gsum only

extern "C" void kernel_launch(void* const* d_in, const int* in_sizes, int n_in,
                              void* d_out, int out_size, void* d_ws, size_t ws_size,
                              hipStream_t stream) {
    const int* eidx = (const int*)d_in[1];
    const int* row0 = eidx;
    const int* col0 = eidx + NE;
    const int* batch = (const int*)d_in[2];
    const float* emb = (const float*)d_in[3];
    const float* pe_w = (const float*)d_in[4];
    const float* pe_b = (const float*)d_in[5];
    const float* proj_w = (const float*)d_in[6];
    const float* proj_b = (const float*)d_in[7];
    const float* gin_w1 = (const float*)d_in[8];
    const float* gin_b1 = (const float*)d_in[9];
    const float* gin_w2 = (const float*)d_in[10];
    const float* gin_b2 = (const float*)d_in[11];
    const float* bn_g = (const float*)d_in[12];
    const float* bn_b = (const float*)d_in[13];
    const float* ffn_w1 = (const float*)d_in[14];
    const float* ffn_b1 = (const float*)d_in[15];
    const float* ffn_w2 = (const float*)d_in[16];
    const float* ffn_b2 = (const float*)d_in[17];
    const float* ffn_bn_g = (const float*)d_in[18];
    const float* ffn_bn_b = (const float*)d_in[19];
    const float* out_w1 = (const float*)d_in[20];
    const float* out_b1 = (const float*)d_in[21];
    const float* out_w2 = (const float*)d_in[22];
    const float* out_b2 = (const float*)d_in[23];
    float* out = (float*)d_out;

    char* ws = (char*)d_ws;
    float*    h     = (float*)(ws + OFF_H);
    ushort_t* hb    = (ushort_t*)(ws + OFF_HB);
    float*    bufF  = (float*)(ws + OFF_BUFF);
    ushort_t* f1h   = (ushort_t*)(ws + OFF_SHARE);
    ushort_t* aggh  = (ushort_t*)(ws + OFF_SHARE);
    ushort_t* z1h   = (ushort_t*)(ws + OFF_SHARE + (size_t)NN * HD * 2);
    int2*     epair = (int2*)(ws + OFF_SHARE);
    float*    rw    = (float*)(ws + OFF_RW);
    float*    p0    = (float*)(ws + OFF_P0);
    float*    p1    = (float*)(ws + OFF_P1);
    float*    pd0   = (float*)(ws + OFF_PD0);
    float*    pd1   = (float*)(ws + OFF_PD1);
    float*    dinv  = (float*)(ws + OFF_DINV);
    int*      esrc  = (int*)(ws + OFF_ESRC);
    int*      rowptr= (int*)(ws + OFF_ROWPTR);
    int*      deg   = (int*)(ws + OFF_DEG);
    int*      bhist = (int*)(ws + OFF_BHIST);
    int*      boffs = (int*)(ws + OFF_BOFFS);
    int*      bsum  = (int*)(ws + OFF_BSUM);
    ushort_t* wt1   = (ushort_t*)(ws + OFF_WT1);
    ushort_t* wt2   = (ushort_t*)(ws + OFF_WT2);
    ushort_t* wt3   = (ushort_t*)(ws + OFF_WT3);
    ushort_t* wt4   = (ushort_t*)(ws + OFF_WT4);
    float*    partS = (float*)(ws + OFF_PARTS);
    float*    partQ = (float*)(ws + OFF_PARTQ);
    float*    stS   = (float*)(ws + OFF_STS);
    float*    stQ   = (float*)(ws + OFF_STQ);
    float*    M     = (float*)(ws + OFF_M);
    float*    c1    = (float*)(ws + OFF_C1);
    int*      cnt   = (int*)(ws + OFF_CNT);
    float*    gsum  = (float*)(ws + OFF_GSUM);

    const int NB = CDIV(NN, 256);   // 391

    hipMemsetAsync(ws + OFF_GSUM, 0, ZERO_BYTES, stream);

    // ---- atomic-free CSR build ----
    k_cnt<<<1, 128, 0, stream>>>(batch, cnt);
    k_bhist<<<NEB, 256, 0, stream>>>(col0, bhist);
    k_gscan1<<<NSB, 256, 0, stream>>>(bhist, bsum);
    k_scan2<<<1, 512, 0, stream>>>(bsum, NSB);
    k_gscan3<<<NSB, 256, 0, stream>>>(bhist, bsum, boffs);
    k_escatter<<<NEB, 256, 0, stream>>>(row0, col0, boffs, epair);
    k_bucket<<<NBKT, 256, 0, stream>>>(epair, boffs, rowptr, deg, esrc);

    // ---- PE + projection ----
    k_init_pe<<<NB, 256, 0, stream>>>(deg, batch, cnt, dinv, p0, pd0);
    k_mc1<<<1, 128, 0, stream>>>(emb, pe_w, pe_b, proj_w, proj_b, M, c1);
    k_prepw<<<1920, 256, 0, stream>>>(gin_w1, gin_w2, ffn_w1, ffn_w2, wt1, wt2, wt3, wt4);
    for (int s = 0; s < WLK; ++s) {
        const float* pin = (s & 1) ? p1 : p0;
        const float* pdin = (s & 1) ? pd1 : pd0;
        float* pout = (s & 1) ? p0 : p1;
        float* pdout = (s & 1) ? pd0 : pd1;
        k_rw_step<<<NB, 256, 0, stream>>>(pin, pdin, rowptr, esrc, dinv,
                                          rw + (size_t)s * NN, pout, pdout);
    }
    k_proj<<<CDIV(NN * HD, 256), 256, 0, stream>>>(rw, M, c1, h, hb);

    // ---- layers ----
    dim3 g1(NBM, 1), g2(NBM, 2);
    for (int i = 0; i < NL; ++i) {
        k_aggb<<<CDIV(NN, 4), 256, 0, stream>>>((const uint_t*)hb, rowptr, esrc, (uint_t*)aggh);
        k_mgemm<128, true, true, false, false><<<g1, 256, 0, stream>>>(
            aggh, wt1 + (size_t)i * 16384, gin_b1 + i * HD, z1h, nullptr, nullptr,
            nullptr, nullptr, 128);
        k_mgemm<128, false, false, false, true><<<g1, 256, 0, stream>>>(
            z1h, wt2 + (size_t)i * 16384, gin_b2 + i * HD, nullptr, bufF, nullptr,
            partS, partQ, 128);
        k_redstats<<<256, 256, 0, stream>>>(partS, partQ, stS, stQ);
        k_bn_relu_res<<<CDIV(NN * HD, 256), 256, 0, stream>>>(
            bufF, stS, stQ, bn_g + i * HD, bn_b + i * HD, h, hb);
        k_mgemm<128, true, true, false, false><<<g2, 256, 0, stream>>>(
            hb, wt3 + (size_t)i * 32768, ffn_b1 + i * 256, f1h, nullptr, nullptr,
            nullptr, nullptr, 256);
        k_mgemm<256, false, false, true, true><<<g1, 256, 0, stream>>>(
            f1h, wt4 + (size_t)i * 32768, ffn_b2 + i * HD, nullptr, bufF, h,
            partS, partQ, 128);
        k_redstats<<<256, 256, 0, stream>>>(partS, partQ, stS, stQ);
        k_bn<<<CDIV(NN * HD, 256), 256, 0, stream>>>(
            bufF, stS, stQ, ffn_bn_g + i * HD, ffn_bn_b + i * HD, h, hb);
    }

    k_pool<<<NB, 128, 0, stream>>>(h, batch, gsum);
    k_head<<<NG, 128, 0, stream>>>(gsum, cnt, out_w1, out_b1, out_w2, out_b2, out);
}

// Round 4
// 1682.446 us; speedup vs baseline: 2.2990x; 1.3158x over previous
//
#include <hip/hip_runtime.h>
#include <math.h>

#define NN 100000
#define NE 1600000
#define NG 128
#define HD 128
#define WLK 16
#define NL 5
#define NOUT 10
#define BNEPS 1e-5f
#define CDIV(a,b) (((a)+(b)-1)/(b))

#define NBKT 782          // buckets of 128 nodes (col>>7)
#define NEB 400           // edge-blocks for bucketing
#define EPB 4000          // edges per edge-block (NEB*EPB == NE)
#define NSCAN (NBKT*NEB)  // 312800
#define NSB CDIV(NSCAN,1024)  // 306
#define NBM 782           // GEMM row-blocks (CDIV(NN,128))

typedef float f32x4 __attribute__((ext_vector_type(4)));
typedef _Float16 f16x8 __attribute__((ext_vector_type(8)));
typedef unsigned short ushort_t;
typedef unsigned int uint_t;

__device__ __forceinline__ ushort_t f2h(float x) {
    union { _Float16 h; ushort_t u; } c;
    c.h = (_Float16)x;                     // v_cvt_f16_f32, RNE
    return c.u;
}
__device__ __forceinline__ float h2f(ushort_t u) {
    union { ushort_t u; _Float16 h; } c;
    c.u = u;
    return (float)c.h;
}

// ---------------- graph-size counts via binary search (batch is sorted) ----------------
__global__ void k_cnt(const int* __restrict__ batch, int* __restrict__ cnt) {
    int g = threadIdx.x;
    if (g >= NG) return;
    int lo0 = 0, hi0 = NN;
    while (lo0 < hi0) { int m = (lo0 + hi0) >> 1; if (batch[m] < g) lo0 = m + 1; else hi0 = m; }
    int lo1 = lo0, hi1 = NN;
    while (lo1 < hi1) { int m = (lo1 + hi1) >> 1; if (batch[m] < g + 1) lo1 = m + 1; else hi1 = m; }
    cnt[g] = lo1 - lo0;
}

// ---------------- atomic-free CSR build: bucket histogram ----------------
__global__ void k_bhist(const int* __restrict__ col0, int* __restrict__ bhist) {
    __shared__ int hist[NBKT];
    for (int i = threadIdx.x; i < NBKT; i += 256) hist[i] = 0;
    __syncthreads();
    int e0 = blockIdx.x * EPB;
    for (int e = e0 + threadIdx.x; e < e0 + EPB; e += 256) atomicAdd(&hist[col0[e] >> 7], 1);
    __syncthreads();
    for (int i = threadIdx.x; i < NBKT; i += 256) bhist[i * NEB + blockIdx.x] = hist[i];
}

// generic exclusive scan over NSCAN ints: chunk-reduce, chunk-sum scan, chunk-scan
__global__ void k_gscan1(const int* __restrict__ in, int* __restrict__ bsum) {
    __shared__ int sm[256];
    int base = blockIdx.x * 1024 + threadIdx.x * 4;
    int s = 0;
#pragma unroll
    for (int i = 0; i < 4; ++i) { int e = base + i; if (e < NSCAN) s += in[e]; }
    sm[threadIdx.x] = s; __syncthreads();
    for (int st = 128; st > 0; st >>= 1) {
        if (threadIdx.x < st) sm[threadIdx.x] += sm[threadIdx.x + st];
        __syncthreads();
    }
    if (threadIdx.x == 0) bsum[blockIdx.x] = sm[0];
}

__global__ void k_scan2(int* __restrict__ blksum, int nblk) {
    __shared__ int sm[512];
    int t = threadIdx.x;
    int x = (t < nblk) ? blksum[t] : 0;
    sm[t] = x; __syncthreads();
    for (int s = 1; s < 512; s <<= 1) {
        int v = (t >= s) ? sm[t - s] : 0;
        __syncthreads();
        sm[t] += v;
        __syncthreads();
    }
    if (t < nblk) blksum[t] = sm[t] - x;   // exclusive
}

__global__ void k_gscan3(const int* __restrict__ in, const int* __restrict__ bsum,
                         int* __restrict__ out) {
    __shared__ int sm[256];
    int t = threadIdx.x;
    int base = blockIdx.x * 1024 + t * 4;
    int v[4]; int s = 0;
#pragma unroll
    for (int i = 0; i < 4; ++i) { int e = base + i; v[i] = (e < NSCAN) ? in[e] : 0; s += v[i]; }
    sm[t] = s; __syncthreads();
    for (int st = 1; st < 256; st <<= 1) {
        int x = (t >= st) ? sm[t - st] : 0;
        __syncthreads();
        sm[t] += x;
        __syncthreads();
    }
    int excl = sm[t] - s + bsum[blockIdx.x];
#pragma unroll
    for (int i = 0; i < 4; ++i) { int e = base + i; if (e < NSCAN) { out[e] = excl; excl += v[i]; } }
}

__global__ void k_escatter(const int* __restrict__ row0, const int* __restrict__ col0,
                           const int* __restrict__ boffs, int2* __restrict__ epair) {
    __shared__ int cur[NBKT];
    for (int i = threadIdx.x; i < NBKT; i += 256) cur[i] = boffs[i * NEB + blockIdx.x];
    __syncthreads();
    int e0 = blockIdx.x * EPB;
    for (int e = e0 + threadIdx.x; e < e0 + EPB; e += 256) {
        int c = col0[e], r = row0[e];
        int pos = atomicAdd(&cur[c >> 7], 1);
        epair[pos] = make_int2(c, r);
    }
}

__global__ void k_bucket(const int2* __restrict__ epair, const int* __restrict__ boffs,
                         int* __restrict__ rowptr, int* __restrict__ deg,
                         int* __restrict__ esrc) {
    __shared__ int cnt_[128], scn[128], cur_[128];
    int bkt = blockIdx.x, t = threadIdx.x;
    int bs = boffs[bkt * NEB];
    int be = (bkt + 1 < NBKT) ? boffs[(bkt + 1) * NEB] : NE;
    if (t < 128) cnt_[t] = 0;
    __syncthreads();
    for (int e = bs + t; e < be; e += 256) atomicAdd(&cnt_[epair[e].x & 127], 1);
    __syncthreads();
    int c = (t < 128) ? cnt_[t] : 0;
    if (t < 128) scn[t] = c;
    __syncthreads();
    for (int st = 1; st < 128; st <<= 1) {
        int x = (t >= st && t < 128) ? scn[t - st] : 0;
        __syncthreads();
        if (t < 128) scn[t] += x;
        __syncthreads();
    }
    if (t < 128) {
        int excl = scn[t] - c;
        int node = bkt * 128 + t;
        if (node < NN) { rowptr[node] = bs + excl; deg[node] = c; }
        cur_[t] = bs + excl;
    }
    if (bkt == NBKT - 1 && t == 0) rowptr[NN] = NE;
    __syncthreads();
    for (int e = bs + t; e < be; e += 256) {
        int2 p = epair[e];
        int pos = atomicAdd(&cur_[p.x & 127], 1);
        esrc[pos] = p.y;
    }
}

// ---------------- PE init ----------------
__global__ void k_init_pe(const int* __restrict__ deg, const int* __restrict__ batch,
                          const int* __restrict__ cnt, float* __restrict__ dinv,
                          float* __restrict__ p, float* __restrict__ pd) {
    int v = blockIdx.x * 256 + threadIdx.x;
    if (v >= NN) return;
    float dv = rsqrtf((float)(deg[v] + 1));   // +1: self-loop
    dinv[v] = dv;
    float pv = 1.0f / fmaxf((float)cnt[batch[v]], 1.0f);
    p[v] = pv; pd[v] = pv * dv;
}

// one RW step; unroll-4 gathers for memory-level parallelism
__global__ void k_rw_step(const float* __restrict__ pin, const float* __restrict__ pdin,
                          const int* __restrict__ rowptr, const int* __restrict__ esrc,
                          const float* __restrict__ dinv, float* __restrict__ rwslice,
                          float* __restrict__ pout, float* __restrict__ pdout) {
    int v = blockIdx.x * 256 + threadIdx.x;
    if (v >= NN) return;
    int b = rowptr[v], e = rowptr[v + 1];
    float a0 = 0.f, a1 = 0.f, a2 = 0.f, a3 = 0.f;
    int i = b;
    for (; i + 4 <= e; i += 4) {
        int s0 = esrc[i], s1 = esrc[i + 1], s2 = esrc[i + 2], s3 = esrc[i + 3];
        a0 += pdin[s0]; a1 += pdin[s1]; a2 += pdin[s2]; a3 += pdin[s3];
    }
    for (; i < e; ++i) a0 += pdin[esrc[i]];
    float s = (a0 + a1) + (a2 + a3);
    float dv = dinv[v];
    float pv = pin[v];
    float np = s * dv + pv * dv * dv;
    float nxt = 0.9f * np + 0.1f * pv;
    rwslice[v] = pv;
    pout[v] = nxt;
    pdout[v] = nxt * dv;
}

__global__ void k_mc1(const float* __restrict__ emb, const float* __restrict__ pe_w,
                      const float* __restrict__ pe_b, const float* __restrict__ proj_w,
                      const float* __restrict__ proj_b, float* __restrict__ M,
                      float* __restrict__ c1) {
    int j = threadIdx.x;
    float c0 = proj_b[j];
    for (int d = 0; d < HD; ++d) c0 += emb[d] * proj_w[d * HD + j];
    for (int w = 0; w < WLK; ++w) c0 += pe_b[w] * proj_w[(HD + w) * HD + j];
    c1[j] = c0;
    for (int s = 0; s < WLK; ++s) {
        float m = 0.f;
        for (int w = 0; w < WLK; ++w) m += pe_w[s * WLK + w] * proj_w[(HD + w) * HD + j];
        M[s * HD + j] = m;
    }
}

// h[v][cg..cg+3] = c1 + sum_s rw[s][v]*M[s][:]   (vec4)
__global__ void k_proj(const float* __restrict__ rw, const float* __restrict__ M,
                       const float* __restrict__ c1, float4* __restrict__ h4,
                       uint2* __restrict__ hb4) {
    int idx = blockIdx.x * 256 + threadIdx.x;   // NN*32
    if (idx >= NN * 32) return;
    int v = idx >> 5, cg = (idx & 31) * 4;
    float4 acc = *(const float4*)&c1[cg];
#pragma unroll
    for (int s = 0; s < WLK; ++s) {
        float r = rw[s * NN + v];
        float4 m = *(const float4*)&M[s * HD + cg];
        acc.x += r * m.x; acc.y += r * m.y; acc.z += r * m.z; acc.w += r * m.w;
    }
    h4[idx] = acc;
    hb4[idx] = make_uint2((uint_t)f2h(acc.x) | ((uint_t)f2h(acc.y) << 16),
                          (uint_t)f2h(acc.z) | ((uint_t)f2h(acc.w) << 16));
}

// cast + transpose all GEMM weights to fp16 [n][k] once per call
__global__ void k_prepw(const float* __restrict__ g1, const float* __restrict__ g2,
                        const float* __restrict__ f1, const float* __restrict__ f2,
                        ushort_t* __restrict__ wt1, ushort_t* __restrict__ wt2,
                        ushort_t* __restrict__ wt3, ushort_t* __restrict__ wt4) {
    int i = blockIdx.x * 256 + threadIdx.x;   // 491520 total
    if (i < 81920) {
        int l = i >> 14, rem = i & 16383, n = rem >> 7, k = rem & 127;
        wt1[i] = f2h(g1[l * 16384 + k * 128 + n]);
    } else if (i < 163840) {
        int j = i - 81920;
        int l = j >> 14, rem = j & 16383, n = rem >> 7, k = rem & 127;
        wt2[j] = f2h(g2[l * 16384 + k * 128 + n]);
    } else if (i < 327680) {
        int j = i - 163840;
        int l = j >> 15, rem = j & 32767, n = rem >> 7, k = rem & 127;
        wt3[j] = f2h(f1[l * 32768 + k * 256 + n]);
    } else {
        int j = i - 327680;
        int l = j >> 15, rem = j & 32767, n = rem >> 8, k = rem & 255;
        wt4[j] = f2h(f2[l * 32768 + k * 128 + n]);
    }
}

// agg[v] = h[v] + sum_j h[src_j]  (fp16 rows, fp32 accumulate, unroll-4 for MLP)
__global__ void k_aggb(const uint_t* __restrict__ hb2, const int* __restrict__ rowptr,
                       const int* __restrict__ esrc, uint_t* __restrict__ aggb2) {
    int wave = threadIdx.x >> 6, lane = threadIdx.x & 63;
    int v = blockIdx.x * 4 + wave;
    if (v >= NN) return;
    uint_t u = hb2[(size_t)v * 64 + lane];
    float sx0 = h2f((ushort_t)(u & 0xFFFFu)), sy0 = h2f((ushort_t)(u >> 16));
    float sx1 = 0.f, sy1 = 0.f, sx2 = 0.f, sy2 = 0.f, sx3 = 0.f, sy3 = 0.f;
    int b = rowptr[v], e = rowptr[v + 1];
    int i = b;
    for (; i + 4 <= e; i += 4) {
        int s0 = esrc[i], s1 = esrc[i + 1], s2 = esrc[i + 2], s3 = esrc[i + 3];
        uint_t x0 = hb2[(size_t)s0 * 64 + lane];
        uint_t x1 = hb2[(size_t)s1 * 64 + lane];
        uint_t x2 = hb2[(size_t)s2 * 64 + lane];
        uint_t x3 = hb2[(size_t)s3 * 64 + lane];
        sx0 += h2f((ushort_t)(x0 & 0xFFFFu)); sy0 += h2f((ushort_t)(x0 >> 16));
        sx1 += h2f((ushort_t)(x1 & 0xFFFFu)); sy1 += h2f((ushort_t)(x1 >> 16));
        sx2 += h2f((ushort_t)(x2 & 0xFFFFu)); sy2 += h2f((ushort_t)(x2 >> 16));
        sx3 += h2f((ushort_t)(x3 & 0xFFFFu)); sy3 += h2f((ushort_t)(x3 >> 16));
    }
    for (; i < e; ++i) {
        uint_t x = hb2[(size_t)esrc[i] * 64 + lane];
        sx0 += h2f((ushort_t)(x & 0xFFFFu)); sy0 += h2f((ushort_t)(x >> 16));
    }
    float sx = (sx0 + sx1) + (sx2 + sx3);
    float sy = (sy0 + sy1) + (sy2 + sy3);
    aggb2[(size_t)v * 64 + lane] = (uint_t)f2h(sx) | ((uint_t)f2h(sy) << 16);
}

// ---------------- fp16 MFMA GEMM: 128x128 tile, 4 waves x (4x4) 16x16x32 frags ----------------
template <int K, bool RELU, bool OUTH16, bool ADDRES, bool DOSTATS>
__global__ __launch_bounds__(256, 2)
void k_mgemm(const ushort_t* __restrict__ A, const ushort_t* __restrict__ WT,
             const float* __restrict__ bias, ushort_t* __restrict__ Ch,
             float* __restrict__ Cf, const float* __restrict__ res,
             float* __restrict__ partS, float* __restrict__ partQ, int ncols) {
    constexpr int LDK = 72;                        // 144B row stride: 16B aligned, spread banks
    __shared__ ushort_t As[128 * LDK];
    __shared__ ushort_t Ws[128 * LDK];
    __shared__ float sS[128], sQ[128];
    const int tid = threadIdx.x;
    const int w = tid >> 6, l = tid & 63;
    const int lm = l & 15, lq = l >> 4;
    const int rb = (w >> 1) * 64, cbw = (w & 1) * 64;
    const int vr0 = blockIdx.x * 128;
    const int cb = blockIdx.y * 128;
    f32x4 acc[4][4] = {};

    for (int kt = 0; kt < K / 64; ++kt) {
        __syncthreads();
#pragma unroll
        for (int it = 0; it < 4; ++it) {
            int f = it * 256 + tid;                // 1024 16B slots per operand
            int row = f >> 3, sl = f & 7;
            uint4 a = make_uint4(0, 0, 0, 0);
            int vr = vr0 + row;
            if (vr < NN) a = *(const uint4*)&A[(size_t)vr * K + kt * 64 + sl * 8];
            *(uint4*)&As[row * LDK + sl * 8] = a;
            uint4 wv = *(const uint4*)&WT[(size_t)(cb + row) * K + kt * 64 + sl * 8];
            *(uint4*)&Ws[row * LDK + sl * 8] = wv;
        }
        __syncthreads();
#pragma unroll
        for (int kk = 0; kk < 64; kk += 32) {
            f16x8 af[4], bf[4];
#pragma unroll
            for (int i = 0; i < 4; ++i)
                af[i] = *(const f16x8*)&As[(rb + i * 16 + lm) * LDK + kk + lq * 8];
#pragma unroll
            for (int j = 0; j < 4; ++j)
                bf[j] = *(const f16x8*)&Ws[(cbw + j * 16 + lm) * LDK + kk + lq * 8];
#pragma unroll
            for (int i = 0; i < 4; ++i)
#pragma unroll
                for (int j = 0; j < 4; ++j)
                    acc[i][j] = __builtin_amdgcn_mfma_f32_16x16x32_f16(af[i], bf[j], acc[i][j], 0, 0, 0);
        }
    }

    float bcol[4];
#pragma unroll
    for (int j = 0; j < 4; ++j) bcol[j] = bias[cb + cbw + j * 16 + lm];
    if (DOSTATS && tid < 128) { sS[tid] = 0.f; sQ[tid] = 0.f; }
    __syncthreads();
    float ls[4] = {0, 0, 0, 0}, lsq[4] = {0, 0, 0, 0};
#pragma unroll
    for (int i = 0; i < 4; ++i) {
#pragma unroll
        for (int r = 0; r < 4; ++r) {
            int vr = vr0 + rb + i * 16 + lq * 4 + r;   // D row = quad*4 + reg
            if (vr < NN) {
#pragma unroll
                for (int j = 0; j < 4; ++j) {
                    float x = acc[i][j][r] + bcol[j];
                    if (RELU) x = fmaxf(x, 0.f);
                    int c = cb + cbw + j * 16 + lm;    // D col = lane&15
                    if (ADDRES) x += res[(size_t)vr * ncols + c];
                    if (DOSTATS) { ls[j] += x; lsq[j] += x * x; }
                    if (OUTH16) Ch[(size_t)vr * ncols + c] = f2h(x);
                    else        Cf[(size_t)vr * ncols + c] = x;
                }
            }
        }
    }
    if (DOSTATS) {
#pragma unroll
        for (int j = 0; j < 4; ++j) {
            atomicAdd(&sS[cbw + j * 16 + lm], ls[j]);
            atomicAdd(&sQ[cbw + j * 16 + lm], lsq[j]);
        }
        __syncthreads();
        if (tid < 128) {
            partS[(size_t)(cb + tid) * NBM + blockIdx.x] = sS[tid];
            partQ[(size_t)(cb + tid) * NBM + blockIdx.x] = sQ[tid];
        }
    }
}

// reduce per-block partial sums -> per-channel BN scale/shift: y = x*bnA[c] + bnB[c]
__global__ void k_bnparm(const float* __restrict__ partS, const float* __restrict__ partQ,
                         const float* __restrict__ g, const float* __restrict__ b,
                         float* __restrict__ bnA, float* __restrict__ bnB) {
    __shared__ float smS[256], smQ[256];
    int c = blockIdx.x, t = threadIdx.x;
    float s = 0.f, q = 0.f;
    for (int i = t; i < NBM; i += 256) {
        s += partS[(size_t)c * NBM + i];
        q += partQ[(size_t)c * NBM + i];
    }
    smS[t] = s; smQ[t] = q; __syncthreads();
    for (int st = 128; st > 0; st >>= 1) {
        if (t < st) { smS[t] += smS[t + st]; smQ[t] += smQ[t + st]; }
        __syncthreads();
    }
    if (t == 0) {
        float mu = smS[0] * (1.0f / NN);
        float var = smQ[0] * (1.0f / NN) - mu * mu;
        float inv = rsqrtf(var + BNEPS);
        float a = g[c] * inv;
        bnA[c] = a;
        bnB[c] = b[c] - mu * a;
    }
}

// GIN post: h += relu(z*A+B);  vec4, refresh fp16 mirror
__global__ void k_bn_relu_res(const float4* __restrict__ z4, const float* __restrict__ bnA,
                              const float* __restrict__ bnB, float4* __restrict__ h4,
                              uint2* __restrict__ hb4) {
    int idx = blockIdx.x * 256 + threadIdx.x;   // NN*32
    if (idx >= NN * 32) return;
    int cg = (idx & 31) * 4;
    float4 A = *(const float4*)&bnA[cg];
    float4 B = *(const float4*)&bnB[cg];
    float4 z = z4[idx], hv = h4[idx];
    float4 nh;
    nh.x = hv.x + fmaxf(z.x * A.x + B.x, 0.f);
    nh.y = hv.y + fmaxf(z.y * A.y + B.y, 0.f);
    nh.z = hv.z + fmaxf(z.z * A.z + B.z, 0.f);
    nh.w = hv.w + fmaxf(z.w * A.w + B.w, 0.f);
    h4[idx] = nh;
    hb4[idx] = make_uint2((uint_t)f2h(nh.x) | ((uint_t)f2h(nh.y) << 16),
                          (uint_t)f2h(nh.z) | ((uint_t)f2h(nh.w) << 16));
}

// FFN post: h = t*A+B;  vec4, refresh fp16 mirror
__global__ void k_bn(const float4* __restrict__ t4, const float* __restrict__ bnA,
                     const float* __restrict__ bnB, float4* __restrict__ h4,
                     uint2* __restrict__ hb4) {
    int idx = blockIdx.x * 256 + threadIdx.x;   // NN*32
    if (idx >= NN * 32) return;
    int cg = (idx & 31) * 4;
    float4 A = *(const float4*)&bnA[cg];
    float4 B = *(const float4*)&bnB[cg];
    float4 t = t4[idx];
    float4 nh;
    nh.x = t.x * A.x + B.x;
    nh.y = t.y * A.y + B.y;
    nh.z = t.z * A.z + B.z;
    nh.w = t.w * A.w + B.w;
    h4[idx] = nh;
    hb4[idx] = make_uint2((uint_t)f2h(nh.x) | ((uint_t)f2h(nh.y) << 16),
                          (uint_t)f2h(nh.z) | ((uint_t)f2h(nh.w) << 16));
}

__global__ void k_pool(const float* __restrict__ h, const int* __restrict__ batch,
                       float* __restrict__ gsum) {
    int c = threadIdx.x;
    int v0 = blockIdx.x * 256;
    if (v0 >= NN) return;
    int vend = (v0 + 256 < NN) ? v0 + 256 : NN;
    float acc = 0.f;
    int bprev = batch[v0];
    for (int v = v0; v < vend; ++v) {
        int bb = batch[v];
        if (bb != bprev) {
            atomicAdd(&gsum[bprev * HD + c], acc);
            acc = 0.f; bprev = bb;
        }
        acc += h[(size_t)v * HD + c];
    }
    atomicAdd(&gsum[bprev * HD + c], acc);
}

__global__ void k_head(const float* __restrict__ gsum, const int* __restrict__ cnt,
                       const float* __restrict__ w1, const float* __restrict__ b1,
                       const float* __restrict__ w2, const float* __restrict__ b2,
                       float* __restrict__ out) {
    __shared__ float gv[HD], av[HD];
    int gid = blockIdx.x, t = threadIdx.x;
    float c = fmaxf((float)cnt[gid], 1.0f);
    gv[t] = gsum[gid * HD + t] / c;
    __syncthreads();
    float a = b1[t];
    for (int k = 0; k < HD; ++k) a += gv[k] * w1[k * HD + t];
    av[t] = fmaxf(a, 0.f);
    __syncthreads();
    if (t < NOUT) {
        float o = b2[t];
        for (int k = 0; k < HD; ++k) o += av[k] * w2[k * NOUT + t];
        out[gid * NOUT + t] = o;
    }
}

// ---------------- workspace layout ----------------
static constexpr size_t AL(size_t x) { return (x + 511) & ~(size_t)511; }
static constexpr size_t OFF_H      = 0;
static constexpr size_t OFF_HB     = OFF_H      + AL((size_t)NN * HD * 4);      // fp32 h
static constexpr size_t OFF_BUFF   = OFF_HB     + AL((size_t)NN * HD * 2);      // fp16 mirror
static constexpr size_t OFF_SHARE  = OFF_BUFF   + AL((size_t)NN * HD * 4);      // z2/t fp32
static constexpr size_t SZ_SHARE   = AL((size_t)NN * 256 * 2);                  // f1h | aggh+z1h | epair
static constexpr size_t OFF_RW     = OFF_SHARE  + SZ_SHARE;
static constexpr size_t OFF_P0     = OFF_RW     + AL((size_t)WLK * NN * 4);
static constexpr size_t OFF_P1     = OFF_P0     + AL((size_t)NN * 4);
static constexpr size_t OFF_PD0    = OFF_P1     + AL((size_t)NN * 4);
static constexpr size_t OFF_PD1    = OFF_PD0    + AL((size_t)NN * 4);
static constexpr size_t OFF_DINV   = OFF_PD1    + AL((size_t)NN * 4);
static constexpr size_t OFF_ESRC   = OFF_DINV   + AL((size_t)NN * 4);
static constexpr size_t OFF_ROWPTR = OFF_ESRC   + AL((size_t)NE * 4);
static constexpr size_t OFF_DEG    = OFF_ROWPTR + AL((size_t)(NN + 1) * 4);
static constexpr size_t OFF_BHIST  = OFF_DEG    + AL((size_t)NN * 4);
static constexpr size_t OFF_BOFFS  = OFF_BHIST  + AL((size_t)NSCAN * 4);
static constexpr size_t OFF_BSUM   = OFF_BOFFS  + AL((size_t)NSCAN * 4);
static constexpr size_t OFF_WT1    = OFF_BSUM   + AL(512 * 4);
static constexpr size_t OFF_WT2    = OFF_WT1    + AL((size_t)5 * 16384 * 2);
static constexpr size_t OFF_WT3    = OFF_WT2    + AL((size_t)5 * 16384 * 2);
static constexpr size_t OFF_WT4    = OFF_WT3    + AL((size_t)5 * 32768 * 2);
static constexpr size_t OFF_PARTS  = OFF_WT4    + AL((size_t)5 * 32768 * 2);
static constexpr size_t OFF_PARTQ  = OFF_PARTS  + AL((size_t)128 * NBM * 4);
static constexpr size_t OFF_BNA    = OFF_PARTQ  + AL((size_t)128 * NBM * 4);
static constexpr size_t OFF_BNB    = OFF_BNA    + AL(128 * 4);
static constexpr size_t OFF_M      = OFF_BNB    + AL(128 * 4);
static constexpr size_t OFF_C1     = OFF_M      + AL((size_t)WLK * HD * 4);
static constexpr size_t OFF_CNT    = OFF_C1     + AL(HD * 4);
static constexpr size_t OFF_GSUM   = OFF_CNT    + AL(NG * 4);
static constexpr size_t ZERO_BYTES = (size_t)NG * HD * 4;                        // gsum only

extern "C" void kernel_launch(void* const* d_in, const int* in_sizes, int n_in,
                              void* d_out, int out_size, void* d_ws, size_t ws_size,
                              hipStream_t stream) {
    const int* eidx = (const int*)d_in[1];
    const int* row0 = eidx;
    const int* col0 = eidx + NE;
    const int* batch = (const int*)d_in[2];
    const float* emb = (const float*)d_in[3];
    const float* pe_w = (const float*)d_in[4];
    const float* pe_b = (const float*)d_in[5];
    const float* proj_w = (const float*)d_in[6];
    const float* proj_b = (const float*)d_in[7];
    const float* gin_w1 = (const float*)d_in[8];
    const float* gin_b1 = (const float*)d_in[9];
    const float* gin_w2 = (const float*)d_in[10];
    const float* gin_b2 = (const float*)d_in[11];
    const float* bn_g = (const float*)d_in[12];
    const float* bn_b = (const float*)d_in[13];
    const float* ffn_w1 = (const float*)d_in[14];
    const float* ffn_b1 = (const float*)d_in[15];
    const float* ffn_w2 = (const float*)d_in[16];
    const float* ffn_b2 = (const float*)d_in[17];
    const float* ffn_bn_g = (const float*)d_in[18];
    const float* ffn_bn_b = (const float*)d_in[19];
    const float* out_w1 = (const float*)d_in[20];
    const float* out_b1 = (const float*)d_in[21];
    const float* out_w2 = (const float*)d_in[22];
    const float* out_b2 = (const float*)d_in[23];
    float* out = (float*)d_out;

    char* ws = (char*)d_ws;
    float*    h     = (float*)(ws + OFF_H);
    ushort_t* hb    = (ushort_t*)(ws + OFF_HB);
    float*    bufF  = (float*)(ws + OFF_BUFF);
    ushort_t* f1h   = (ushort_t*)(ws + OFF_SHARE);
    ushort_t* aggh  = (ushort_t*)(ws + OFF_SHARE);
    ushort_t* z1h   = (ushort_t*)(ws + OFF_SHARE + (size_t)NN * HD * 2);
    int2*     epair = (int2*)(ws + OFF_SHARE);
    float*    rw    = (float*)(ws + OFF_RW);
    float*    p0    = (float*)(ws + OFF_P0);
    float*    p1    = (float*)(ws + OFF_P1);
    float*    pd0   = (float*)(ws + OFF_PD0);
    float*    pd1   = (float*)(ws + OFF_PD1);
    float*    dinv  = (float*)(ws + OFF_DINV);
    int*      esrc  = (int*)(ws + OFF_ESRC);
    int*      rowptr= (int*)(ws + OFF_ROWPTR);
    int*      deg   = (int*)(ws + OFF_DEG);
    int*      bhist = (int*)(ws + OFF_BHIST);
    int*      boffs = (int*)(ws + OFF_BOFFS);
    int*      bsum  = (int*)(ws + OFF_BSUM);
    ushort_t* wt1   = (ushort_t*)(ws + OFF_WT1);
    ushort_t* wt2   = (ushort_t*)(ws + OFF_WT2);
    ushort_t* wt3   = (ushort_t*)(ws + OFF_WT3);
    ushort_t* wt4   = (ushort_t*)(ws + OFF_WT4);
    float*    partS = (float*)(ws + OFF_PARTS);
    float*    partQ = (float*)(ws + OFF_PARTQ);
    float*    bnA   = (float*)(ws + OFF_BNA);
    float*    bnB   = (float*)(ws + OFF_BNB);
    float*    M     = (float*)(ws + OFF_M);
    float*    c1    = (float*)(ws + OFF_C1);
    int*      cnt   = (int*)(ws + OFF_CNT);
    float*    gsum  = (float*)(ws + OFF_GSUM);

    const int NB = CDIV(NN, 256);        // 391
    const int NBV = CDIV(NN * 32, 256);  // 12500 (vec4 elementwise)

    hipMemsetAsync(ws + OFF_GSUM, 0, ZERO_BYTES, stream);

    // ---- atomic-free CSR build ----
    k_cnt<<<1, 128, 0, stream>>>(batch, cnt);
    k_bhist<<<NEB, 256, 0, stream>>>(col0, bhist);
    k_gscan1<<<NSB, 256, 0, stream>>>(bhist, bsum);
    k_scan2<<<1, 512, 0, stream>>>(bsum, NSB);
    k_gscan3<<<NSB, 256, 0, stream>>>(bhist, bsum, boffs);
    k_escatter<<<NEB, 256, 0, stream>>>(row0, col0, boffs, epair);
    k_bucket<<<NBKT, 256, 0, stream>>>(epair, boffs, rowptr, deg, esrc);

    // ---- PE + projection ----
    k_init_pe<<<NB, 256, 0, stream>>>(deg, batch, cnt, dinv, p0, pd0);
    k_mc1<<<1, 128, 0, stream>>>(emb, pe_w, pe_b, proj_w, proj_b, M, c1);
    k_prepw<<<1920, 256, 0, stream>>>(gin_w1, gin_w2, ffn_w1, ffn_w2, wt1, wt2, wt3, wt4);
    for (int s = 0; s < WLK; ++s) {
        const float* pin = (s & 1) ? p1 : p0;
        const float* pdin = (s & 1) ? pd1 : pd0;
        float* pout = (s & 1) ? p0 : p1;
        float* pdout = (s & 1) ? pd0 : pd1;
        k_rw_step<<<NB, 256, 0, stream>>>(pin, pdin, rowptr, esrc, dinv,
                                          rw + (size_t)s * NN, pout, pdout);
    }
    k_proj<<<NBV, 256, 0, stream>>>(rw, M, c1, (float4*)h, (uint2*)hb);

    // ---- layers ----
    dim3 g1(NBM, 1), g2(NBM, 2);
    for (int i = 0; i < NL; ++i) {
        k_aggb<<<CDIV(NN, 4), 256, 0, stream>>>((const uint_t*)hb, rowptr, esrc, (uint_t*)aggh);
        k_mgemm<128, true, true, false, false><<<g1, 256, 0, stream>>>(
            aggh, wt1 + (size_t)i * 16384, gin_b1 + i * HD, z1h, nullptr, nullptr,
            nullptr, nullptr, 128);
        k_mgemm<128, false, false, false, true><<<g1, 256, 0, stream>>>(
            z1h, wt2 + (size_t)i * 16384, gin_b2 + i * HD, nullptr, bufF, nullptr,
            partS, partQ, 128);
        k_bnparm<<<128, 256, 0, stream>>>(partS, partQ, bn_g + i * HD, bn_b + i * HD, bnA, bnB);
        k_bn_relu_res<<<NBV, 256, 0, stream>>>(
            (const float4*)bufF, bnA, bnB, (float4*)h, (uint2*)hb);
        k_mgemm<128, true, true, false, false><<<g2, 256, 0, stream>>>(
            hb, wt3 + (size_t)i * 32768, ffn_b1 + i * 256, f1h, nullptr, nullptr,
            nullptr, nullptr, 256);
        k_mgemm<256, false, false, true, true><<<g1, 256, 0, stream>>>(
            f1h, wt4 + (size_t)i * 32768, ffn_b2 + i * HD, nullptr, bufF, h,
            partS, partQ, 128);
        k_bnparm<<<128, 256, 0, stream>>>(partS, partQ, ffn_bn_g + i * HD, ffn_bn_b + i * HD, bnA, bnB);
        k_bn<<<NBV, 256, 0, stream>>>(
            (const float4*)bufF, bnA, bnB, (float4*)h, (uint2*)hb);
    }

    k_pool<<<NB, 128, 0, stream>>>(h, batch, gsum);
    k_head<<<NG, 128, 0, stream>>>(gsum, cnt, out_w1, out_b1, out_w2, out_b2, out);
}

// Round 5
// 1620.431 us; speedup vs baseline: 2.3870x; 1.0383x over previous
//
#include <hip/hip_runtime.h>
#include <math.h>

#define NN 100000
#define NE 1600000
#define NG 128
#define HD 128
#define WLK 16
#define NL 5
#define NOUT 10
#define BNEPS 1e-5f
#define CDIV(a,b) (((a)+(b)-1)/(b))

#define NBKT 782          // buckets of 128 nodes (col>>7)
#define NEB 400           // edge-blocks for bucketing
#define EPB 4000          // edges per edge-block (NEB*EPB == NE)
#define NSCAN (NBKT*NEB)  // 312800
#define NSB CDIV(NSCAN,1024)  // 306
#define NBM 782           // GEMM row-blocks (CDIV(NN,128))

typedef float f32x4 __attribute__((ext_vector_type(4)));
typedef _Float16 f16x8 __attribute__((ext_vector_type(8)));
typedef unsigned short ushort_t;
typedef unsigned int uint_t;

__device__ __forceinline__ ushort_t f2h(float x) {
    union { _Float16 h; ushort_t u; } c;
    c.h = (_Float16)x;                     // v_cvt_f16_f32, RNE
    return c.u;
}
__device__ __forceinline__ float h2f(ushort_t u) {
    union { ushort_t u; _Float16 h; } c;
    c.u = u;
    return (float)c.h;
}

// ---------------- graph counts + start offsets via binary search (batch sorted) ----------------
__global__ void k_cnt(const int* __restrict__ batch, int* __restrict__ cnt,
                      int* __restrict__ goff) {
    int g = threadIdx.x;
    if (g >= NG) return;
    int lo0 = 0, hi0 = NN;
    while (lo0 < hi0) { int m = (lo0 + hi0) >> 1; if (batch[m] < g) lo0 = m + 1; else hi0 = m; }
    int lo1 = lo0, hi1 = NN;
    while (lo1 < hi1) { int m = (lo1 + hi1) >> 1; if (batch[m] < g + 1) lo1 = m + 1; else hi1 = m; }
    cnt[g] = lo1 - lo0;
    goff[g] = lo0;
}

// ---------------- atomic-free CSR build: bucket histogram ----------------
__global__ void k_bhist(const int* __restrict__ col0, int* __restrict__ bhist) {
    __shared__ int hist[NBKT];
    for (int i = threadIdx.x; i < NBKT; i += 256) hist[i] = 0;
    __syncthreads();
    int e0 = blockIdx.x * EPB;
    for (int e = e0 + threadIdx.x; e < e0 + EPB; e += 256) atomicAdd(&hist[col0[e] >> 7], 1);
    __syncthreads();
    for (int i = threadIdx.x; i < NBKT; i += 256) bhist[i * NEB + blockIdx.x] = hist[i];
}

__global__ void k_gscan1(const int* __restrict__ in, int* __restrict__ bsum) {
    __shared__ int sm[256];
    int base = blockIdx.x * 1024 + threadIdx.x * 4;
    int s = 0;
#pragma unroll
    for (int i = 0; i < 4; ++i) { int e = base + i; if (e < NSCAN) s += in[e]; }
    sm[threadIdx.x] = s; __syncthreads();
    for (int st = 128; st > 0; st >>= 1) {
        if (threadIdx.x < st) sm[threadIdx.x] += sm[threadIdx.x + st];
        __syncthreads();
    }
    if (threadIdx.x == 0) bsum[blockIdx.x] = sm[0];
}

__global__ void k_scan2(int* __restrict__ blksum, int nblk) {
    __shared__ int sm[512];
    int t = threadIdx.x;
    int x = (t < nblk) ? blksum[t] : 0;
    sm[t] = x; __syncthreads();
    for (int s = 1; s < 512; s <<= 1) {
        int v = (t >= s) ? sm[t - s] : 0;
        __syncthreads();
        sm[t] += v;
        __syncthreads();
    }
    if (t < nblk) blksum[t] = sm[t] - x;   // exclusive
}

__global__ void k_gscan3(const int* __restrict__ in, const int* __restrict__ bsum,
                         int* __restrict__ out) {
    __shared__ int sm[256];
    int t = threadIdx.x;
    int base = blockIdx.x * 1024 + t * 4;
    int v[4]; int s = 0;
#pragma unroll
    for (int i = 0; i < 4; ++i) { int e = base + i; v[i] = (e < NSCAN) ? in[e] : 0; s += v[i]; }
    sm[t] = s; __syncthreads();
    for (int st = 1; st < 256; st <<= 1) {
        int x = (t >= st) ? sm[t - st] : 0;
        __syncthreads();
        sm[t] += x;
        __syncthreads();
    }
    int excl = sm[t] - s + bsum[blockIdx.x];
#pragma unroll
    for (int i = 0; i < 4; ++i) { int e = base + i; if (e < NSCAN) { out[e] = excl; excl += v[i]; } }
}

__global__ void k_escatter(const int* __restrict__ row0, const int* __restrict__ col0,
                           const int* __restrict__ boffs, int2* __restrict__ epair) {
    __shared__ int cur[NBKT];
    for (int i = threadIdx.x; i < NBKT; i += 256) cur[i] = boffs[i * NEB + blockIdx.x];
    __syncthreads();
    int e0 = blockIdx.x * EPB;
    for (int e = e0 + threadIdx.x; e < e0 + EPB; e += 256) {
        int c = col0[e], r = row0[e];
        int pos = atomicAdd(&cur[c >> 7], 1);
        epair[pos] = make_int2(c, r);
    }
}

__global__ void k_bucket(const int2* __restrict__ epair, const int* __restrict__ boffs,
                         int* __restrict__ rowptr, int* __restrict__ deg,
                         int* __restrict__ esrc) {
    __shared__ int cnt_[128], scn[128], cur_[128];
    int bkt = blockIdx.x, t = threadIdx.x;
    int bs = boffs[bkt * NEB];
    int be = (bkt + 1 < NBKT) ? boffs[(bkt + 1) * NEB] : NE;
    if (t < 128) cnt_[t] = 0;
    __syncthreads();
    for (int e = bs + t; e < be; e += 256) atomicAdd(&cnt_[epair[e].x & 127], 1);
    __syncthreads();
    int c = (t < 128) ? cnt_[t] : 0;
    if (t < 128) scn[t] = c;
    __syncthreads();
    for (int st = 1; st < 128; st <<= 1) {
        int x = (t >= st && t < 128) ? scn[t - st] : 0;
        __syncthreads();
        if (t < 128) scn[t] += x;
        __syncthreads();
    }
    if (t < 128) {
        int excl = scn[t] - c;
        int node = bkt * 128 + t;
        if (node < NN) { rowptr[node] = bs + excl; deg[node] = c; }
        cur_[t] = bs + excl;
    }
    if (bkt == NBKT - 1 && t == 0) rowptr[NN] = NE;
    __syncthreads();
    for (int e = bs + t; e < be; e += 256) {
        int2 p = epair[e];
        int pos = atomicAdd(&cur_[p.x & 127], 1);
        esrc[pos] = p.y;
    }
}

// ---------------- PE init ----------------
__global__ void k_init_pe(const int* __restrict__ deg, const int* __restrict__ batch,
                          const int* __restrict__ cnt, float* __restrict__ dinv,
                          float* __restrict__ p, float* __restrict__ pd) {
    int v = blockIdx.x * 256 + threadIdx.x;
    if (v >= NN) return;
    float dv = rsqrtf((float)(deg[v] + 1));   // +1: self-loop
    dinv[v] = dv;
    float pv = 1.0f / fmaxf((float)cnt[batch[v]], 1.0f);
    p[v] = pv; pd[v] = pv * dv;
}

// one RW step; unroll-4 gathers for memory-level parallelism
__global__ void k_rw_step(const float* __restrict__ pin, const float* __restrict__ pdin,
                          const int* __restrict__ rowptr, const int* __restrict__ esrc,
                          const float* __restrict__ dinv, float* __restrict__ rwslice,
                          float* __restrict__ pout, float* __restrict__ pdout) {
    int v = blockIdx.x * 256 + threadIdx.x;
    if (v >= NN) return;
    int b = rowptr[v], e = rowptr[v + 1];
    float a0 = 0.f, a1 = 0.f, a2 = 0.f, a3 = 0.f;
    int i = b;
    for (; i + 4 <= e; i += 4) {
        int s0 = esrc[i], s1 = esrc[i + 1], s2 = esrc[i + 2], s3 = esrc[i + 3];
        a0 += pdin[s0]; a1 += pdin[s1]; a2 += pdin[s2]; a3 += pdin[s3];
    }
    for (; i < e; ++i) a0 += pdin[esrc[i]];
    float s = (a0 + a1) + (a2 + a3);
    float dv = dinv[v];
    float pv = pin[v];
    float np = s * dv + pv * dv * dv;
    float nxt = 0.9f * np + 0.1f * pv;
    rwslice[v] = pv;
    pout[v] = nxt;
    pdout[v] = nxt * dv;
}

__global__ void k_mc1(const float* __restrict__ emb, const float* __restrict__ pe_w,
                      const float* __restrict__ pe_b, const float* __restrict__ proj_w,
                      const float* __restrict__ proj_b, float* __restrict__ M,
                      float* __restrict__ c1) {
    int j = threadIdx.x;
    float c0 = proj_b[j];
    for (int d = 0; d < HD; ++d) c0 += emb[d] * proj_w[d * HD + j];
    for (int w = 0; w < WLK; ++w) c0 += pe_b[w] * proj_w[(HD + w) * HD + j];
    c1[j] = c0;
    for (int s = 0; s < WLK; ++s) {
        float m = 0.f;
        for (int w = 0; w < WLK; ++w) m += pe_w[s * WLK + w] * proj_w[(HD + w) * HD + j];
        M[s * HD + j] = m;
    }
}

// h[v][cg..cg+3] = c1 + sum_s rw[s][v]*M[s][:]   (vec4)
__global__ void k_proj(const float* __restrict__ rw, const float* __restrict__ M,
                       const float* __restrict__ c1, float4* __restrict__ h4,
                       uint2* __restrict__ hb4) {
    int idx = blockIdx.x * 256 + threadIdx.x;   // NN*32
    if (idx >= NN * 32) return;
    int v = idx >> 5, cg = (idx & 31) * 4;
    float4 acc = *(const float4*)&c1[cg];
#pragma unroll
    for (int s = 0; s < WLK; ++s) {
        float r = rw[s * NN + v];
        float4 m = *(const float4*)&M[s * HD + cg];
        acc.x += r * m.x; acc.y += r * m.y; acc.z += r * m.z; acc.w += r * m.w;
    }
    h4[idx] = acc;
    hb4[idx] = make_uint2((uint_t)f2h(acc.x) | ((uint_t)f2h(acc.y) << 16),
                          (uint_t)f2h(acc.z) | ((uint_t)f2h(acc.w) << 16));
}

// cast + transpose all GEMM weights to fp16 [n][k] once per call
__global__ void k_prepw(const float* __restrict__ g1, const float* __restrict__ g2,
                        const float* __restrict__ f1, const float* __restrict__ f2,
                        ushort_t* __restrict__ wt1, ushort_t* __restrict__ wt2,
                        ushort_t* __restrict__ wt3, ushort_t* __restrict__ wt4) {
    int i = blockIdx.x * 256 + threadIdx.x;   // 491520 total
    if (i < 81920) {
        int l = i >> 14, rem = i & 16383, n = rem >> 7, k = rem & 127;
        wt1[i] = f2h(g1[l * 16384 + k * 128 + n]);
    } else if (i < 163840) {
        int j = i - 81920;
        int l = j >> 14, rem = j & 16383, n = rem >> 7, k = rem & 127;
        wt2[j] = f2h(g2[l * 16384 + k * 128 + n]);
    } else if (i < 327680) {
        int j = i - 163840;
        int l = j >> 15, rem = j & 32767, n = rem >> 7, k = rem & 127;
        wt3[j] = f2h(f1[l * 32768 + k * 256 + n]);
    } else {
        int j = i - 327680;
        int l = j >> 15, rem = j & 32767, n = rem >> 8, k = rem & 255;
        wt4[j] = f2h(f2[l * 32768 + k * 128 + n]);
    }
}

// agg[v] = h[v] + sum_j h[src_j]  (fp16 rows, fp32 accumulate, unroll-8 for MLP)
__global__ void k_aggb(const uint_t* __restrict__ hb2, const int* __restrict__ rowptr,
                       const int* __restrict__ esrc, uint_t* __restrict__ aggb2) {
    int wave = threadIdx.x >> 6, lane = threadIdx.x & 63;
    int v = blockIdx.x * 4 + wave;
    if (v >= NN) return;
    uint_t u = hb2[(size_t)v * 64 + lane];
    float sx[8], sy[8];
#pragma unroll
    for (int k = 0; k < 8; ++k) { sx[k] = 0.f; sy[k] = 0.f; }
    sx[0] = h2f((ushort_t)(u & 0xFFFFu)); sy[0] = h2f((ushort_t)(u >> 16));
    int b = rowptr[v], e = rowptr[v + 1];
    int i = b;
    for (; i + 8 <= e; i += 8) {
        int idx[8]; uint_t x[8];
#pragma unroll
        for (int k = 0; k < 8; ++k) idx[k] = esrc[i + k];
#pragma unroll
        for (int k = 0; k < 8; ++k) x[k] = hb2[(size_t)idx[k] * 64 + lane];
#pragma unroll
        for (int k = 0; k < 8; ++k) {
            sx[k] += h2f((ushort_t)(x[k] & 0xFFFFu));
            sy[k] += h2f((ushort_t)(x[k] >> 16));
        }
    }
    for (; i < e; ++i) {
        uint_t x = hb2[(size_t)esrc[i] * 64 + lane];
        sx[0] += h2f((ushort_t)(x & 0xFFFFu)); sy[0] += h2f((ushort_t)(x >> 16));
    }
    float fx = ((sx[0] + sx[1]) + (sx[2] + sx[3])) + ((sx[4] + sx[5]) + (sx[6] + sx[7]));
    float fy = ((sy[0] + sy[1]) + (sy[2] + sy[3])) + ((sy[4] + sy[5]) + (sy[6] + sy[7]));
    aggb2[(size_t)v * 64 + lane] = (uint_t)f2h(fx) | ((uint_t)f2h(fy) << 16);
}

// ---------------- fused GIN MLP: z2 = (relu(agg@W1+b1))@W2+b2, z1 stays in LDS ----------------
#define GLDK 136
__global__ __launch_bounds__(256)
void k_gin(const ushort_t* __restrict__ A, const ushort_t* __restrict__ W1T,
           const ushort_t* __restrict__ W2T, const float* __restrict__ b1,
           const float* __restrict__ b2, ushort_t* __restrict__ z2h,
           float* __restrict__ partS, float* __restrict__ partQ) {
    __shared__ ushort_t As[128 * GLDK];   // A tile, later reused for z1 (A-layout)
    __shared__ ushort_t Ws[64 * GLDK];    // weight chunk (64 output-cols x K=128)
    __shared__ float sS[128], sQ[128];
    const int tid = threadIdx.x;
    const int w = tid >> 6, l = tid & 63;
    const int lm = l & 15, lq = l >> 4;
    const int rw0 = w * 32;               // wave's 32-row strip
    const int vr0 = blockIdx.x * 128;
    if (tid < 128) { sS[tid] = 0.f; sQ[tid] = 0.f; }

    // stage A tile (K=128 all at once)
#pragma unroll
    for (int it = 0; it < 8; ++it) {
        int f = it * 256 + tid;           // 2048 16B slots
        int row = f >> 4, sl = f & 15;
        uint4 a = make_uint4(0, 0, 0, 0);
        int vr = vr0 + row;
        if (vr < NN) a = *(const uint4*)&A[(size_t)vr * HD + sl * 8];
        *(uint4*)&As[row * GLDK + sl * 8] = a;
    }

    // phase 1: z1 = A @ W1 (col chunks of 64)
    f32x4 z1a[2][2][4] = {};
    for (int c = 0; c < 2; ++c) {
        __syncthreads();
#pragma unroll
        for (int it = 0; it < 4; ++it) {
            int f = it * 256 + tid;
            int row = f >> 4, sl = f & 15;
            *(uint4*)&Ws[row * GLDK + sl * 8] =
                *(const uint4*)&W1T[(size_t)(c * 64 + row) * HD + sl * 8];
        }
        __syncthreads();
#pragma unroll
        for (int kk = 0; kk < 128; kk += 32) {
            f16x8 af[2], bf[4];
#pragma unroll
            for (int i = 0; i < 2; ++i)
                af[i] = *(const f16x8*)&As[(rw0 + i * 16 + lm) * GLDK + kk + lq * 8];
#pragma unroll
            for (int j = 0; j < 4; ++j)
                bf[j] = *(const f16x8*)&Ws[(j * 16 + lm) * GLDK + kk + lq * 8];
#pragma unroll
            for (int i = 0; i < 2; ++i)
#pragma unroll
                for (int j = 0; j < 4; ++j)
                    z1a[c][i][j] = __builtin_amdgcn_mfma_f32_16x16x32_f16(af[i], bf[j], z1a[c][i][j], 0, 0, 0);
        }
    }
    __syncthreads();                       // all A reads done; safe to overwrite with z1

    // write z1 = relu(z1a + b1) back into As in A-fragment layout
#pragma unroll
    for (int c = 0; c < 2; ++c)
#pragma unroll
        for (int j = 0; j < 4; ++j) {
            int col = c * 64 + j * 16 + lm;
            float bj = b1[col];
#pragma unroll
            for (int i = 0; i < 2; ++i)
#pragma unroll
                for (int r = 0; r < 4; ++r) {
                    int row = rw0 + i * 16 + lq * 4 + r;
                    As[row * GLDK + col] = f2h(fmaxf(z1a[c][i][j][r] + bj, 0.f));
                }
        }

    // phase 2: z2 = z1 @ W2
    f32x4 z2a[2][2][4] = {};
    for (int c2 = 0; c2 < 2; ++c2) {
        __syncthreads();
#pragma unroll
        for (int it = 0; it < 4; ++it) {
            int f = it * 256 + tid;
            int row = f >> 4, sl = f & 15;
            *(uint4*)&Ws[row * GLDK + sl * 8] =
                *(const uint4*)&W2T[(size_t)(c2 * 64 + row) * HD + sl * 8];
        }
        __syncthreads();
#pragma unroll
        for (int kk = 0; kk < 128; kk += 32) {
            f16x8 af[2], bf[4];
#pragma unroll
            for (int i = 0; i < 2; ++i)
                af[i] = *(const f16x8*)&As[(rw0 + i * 16 + lm) * GLDK + kk + lq * 8];
#pragma unroll
            for (int j = 0; j < 4; ++j)
                bf[j] = *(const f16x8*)&Ws[(j * 16 + lm) * GLDK + kk + lq * 8];
#pragma unroll
            for (int i = 0; i < 2; ++i)
#pragma unroll
                for (int j = 0; j < 4; ++j)
                    z2a[c2][i][j] = __builtin_amdgcn_mfma_f32_16x16x32_f16(af[i], bf[j], z2a[c2][i][j], 0, 0, 0);
        }
    }

    // epilogue: bias + fp16 store + BN partial stats
    float ls[2][4] = {}, lsq[2][4] = {};
#pragma unroll
    for (int c2 = 0; c2 < 2; ++c2)
#pragma unroll
        for (int j = 0; j < 4; ++j) {
            int col = c2 * 64 + j * 16 + lm;
            float bj = b2[col];
#pragma unroll
            for (int i = 0; i < 2; ++i)
#pragma unroll
                for (int r = 0; r < 4; ++r) {
                    int vr = vr0 + rw0 + i * 16 + lq * 4 + r;
                    if (vr < NN) {
                        float x = z2a[c2][i][j][r] + bj;
                        ls[c2][j] += x; lsq[c2][j] += x * x;
                        z2h[(size_t)vr * HD + col] = f2h(x);
                    }
                }
        }
#pragma unroll
    for (int c2 = 0; c2 < 2; ++c2)
#pragma unroll
        for (int j = 0; j < 4; ++j) {
            atomicAdd(&sS[c2 * 64 + j * 16 + lm], ls[c2][j]);
            atomicAdd(&sQ[c2 * 64 + j * 16 + lm], lsq[c2][j]);
        }
    __syncthreads();
    if (tid < 128) {
        partS[(size_t)tid * NBM + blockIdx.x] = sS[tid];
        partQ[(size_t)tid * NBM + blockIdx.x] = sQ[tid];
    }
}

// ---------------- fp16 MFMA GEMM: 128x128 tile, 4 waves x (4x4) 16x16x32 frags ----------------
template <int K, bool RELU, bool OUTH16, bool ADDRES, bool DOSTATS>
__global__ __launch_bounds__(256, 2)
void k_mgemm(const ushort_t* __restrict__ A, const ushort_t* __restrict__ WT,
             const float* __restrict__ bias, ushort_t* __restrict__ Ch,
             float* __restrict__ Cf, const float* __restrict__ res,
             float* __restrict__ partS, float* __restrict__ partQ, int ncols) {
    constexpr int LDK = 72;                        // 144B row stride: 16B aligned, spread banks
    __shared__ ushort_t As[128 * LDK];
    __shared__ ushort_t Ws[128 * LDK];
    __shared__ float sS[128], sQ[128];
    const int tid = threadIdx.x;
    const int w = tid >> 6, l = tid & 63;
    const int lm = l & 15, lq = l >> 4;
    const int rb = (w >> 1) * 64, cbw = (w & 1) * 64;
    const int vr0 = blockIdx.x * 128;
    const int cb = blockIdx.y * 128;
    f32x4 acc[4][4] = {};

    for (int kt = 0; kt < K / 64; ++kt) {
        __syncthreads();
#pragma unroll
        for (int it = 0; it < 4; ++it) {
            int f = it * 256 + tid;                // 1024 16B slots per operand
            int row = f >> 3, sl = f & 7;
            uint4 a = make_uint4(0, 0, 0, 0);
            int vr = vr0 + row;
            if (vr < NN) a = *(const uint4*)&A[(size_t)vr * K + kt * 64 + sl * 8];
            *(uint4*)&As[row * LDK + sl * 8] = a;
            uint4 wv = *(const uint4*)&WT[(size_t)(cb + row) * K + kt * 64 + sl * 8];
            *(uint4*)&Ws[row * LDK + sl * 8] = wv;
        }
        __syncthreads();
#pragma unroll
        for (int kk = 0; kk < 64; kk += 32) {
            f16x8 af[4], bf[4];
#pragma unroll
            for (int i = 0; i < 4; ++i)
                af[i] = *(const f16x8*)&As[(rb + i * 16 + lm) * LDK + kk + lq * 8];
#pragma unroll
            for (int j = 0; j < 4; ++j)
                bf[j] = *(const f16x8*)&Ws[(cbw + j * 16 + lm) * LDK + kk + lq * 8];
#pragma unroll
            for (int i = 0; i < 4; ++i)
#pragma unroll
                for (int j = 0; j < 4; ++j)
                    acc[i][j] = __builtin_amdgcn_mfma_f32_16x16x32_f16(af[i], bf[j], acc[i][j], 0, 0, 0);
        }
    }

    float bcol[4];
#pragma unroll
    for (int j = 0; j < 4; ++j) bcol[j] = bias[cb + cbw + j * 16 + lm];
    if (DOSTATS && tid < 128) { sS[tid] = 0.f; sQ[tid] = 0.f; }
    __syncthreads();
    float ls[4] = {0, 0, 0, 0}, lsq[4] = {0, 0, 0, 0};
#pragma unroll
    for (int i = 0; i < 4; ++i) {
#pragma unroll
        for (int r = 0; r < 4; ++r) {
            int vr = vr0 + rb + i * 16 + lq * 4 + r;   // D row = quad*4 + reg
            if (vr < NN) {
#pragma unroll
                for (int j = 0; j < 4; ++j) {
                    float x = acc[i][j][r] + bcol[j];
                    if (RELU) x = fmaxf(x, 0.f);
                    int c = cb + cbw + j * 16 + lm;    // D col = lane&15
                    if (ADDRES) x += res[(size_t)vr * ncols + c];
                    if (DOSTATS) { ls[j] += x; lsq[j] += x * x; }
                    if (OUTH16) Ch[(size_t)vr * ncols + c] = f2h(x);
                    else        Cf[(size_t)vr * ncols + c] = x;
                }
            }
        }
    }
    if (DOSTATS) {
#pragma unroll
        for (int j = 0; j < 4; ++j) {
            atomicAdd(&sS[cbw + j * 16 + lm], ls[j]);
            atomicAdd(&sQ[cbw + j * 16 + lm], lsq[j]);
        }
        __syncthreads();
        if (tid < 128) {
            partS[(size_t)(cb + tid) * NBM + blockIdx.x] = sS[tid];
            partQ[(size_t)(cb + tid) * NBM + blockIdx.x] = sQ[tid];
        }
    }
}

// reduce per-block partial sums -> per-channel BN scale/shift: y = x*bnA[c] + bnB[c]
__global__ void k_bnparm(const float* __restrict__ partS, const float* __restrict__ partQ,
                         const float* __restrict__ g, const float* __restrict__ b,
                         float* __restrict__ bnA, float* __restrict__ bnB) {
    __shared__ float smS[256], smQ[256];
    int c = blockIdx.x, t = threadIdx.x;
    float s = 0.f, q = 0.f;
    for (int i = t; i < NBM; i += 256) {
        s += partS[(size_t)c * NBM + i];
        q += partQ[(size_t)c * NBM + i];
    }
    smS[t] = s; smQ[t] = q; __syncthreads();
    for (int st = 128; st > 0; st >>= 1) {
        if (t < st) { smS[t] += smS[t + st]; smQ[t] += smQ[t + st]; }
        __syncthreads();
    }
    if (t == 0) {
        float mu = smS[0] * (1.0f / NN);
        float var = smQ[0] * (1.0f / NN) - mu * mu;
        float inv = rsqrtf(var + BNEPS);
        float a = g[c] * inv;
        bnA[c] = a;
        bnB[c] = b[c] - mu * a;
    }
}

// GIN post: h += relu(z*A+B);  z fp16, vec4, refresh fp16 mirror
__global__ void k_bn_relu_res(const uint2* __restrict__ z4, const float* __restrict__ bnA,
                              const float* __restrict__ bnB, float4* __restrict__ h4,
                              uint2* __restrict__ hb4) {
    int idx = blockIdx.x * 256 + threadIdx.x;   // NN*32
    if (idx >= NN * 32) return;
    int cg = (idx & 31) * 4;
    float4 A = *(const float4*)&bnA[cg];
    float4 B = *(const float4*)&bnB[cg];
    uint2 zv = z4[idx];
    float z0 = h2f((ushort_t)(zv.x & 0xFFFFu)), z1 = h2f((ushort_t)(zv.x >> 16));
    float z2 = h2f((ushort_t)(zv.y & 0xFFFFu)), z3 = h2f((ushort_t)(zv.y >> 16));
    float4 hv = h4[idx];
    float4 nh;
    nh.x = hv.x + fmaxf(z0 * A.x + B.x, 0.f);
    nh.y = hv.y + fmaxf(z1 * A.y + B.y, 0.f);
    nh.z = hv.z + fmaxf(z2 * A.z + B.z, 0.f);
    nh.w = hv.w + fmaxf(z3 * A.w + B.w, 0.f);
    h4[idx] = nh;
    hb4[idx] = make_uint2((uint_t)f2h(nh.x) | ((uint_t)f2h(nh.y) << 16),
                          (uint_t)f2h(nh.z) | ((uint_t)f2h(nh.w) << 16));
}

// FFN post: h = t*A+B;  t fp16, vec4, refresh fp16 mirror
__global__ void k_bn(const uint2* __restrict__ t4, const float* __restrict__ bnA,
                     const float* __restrict__ bnB, float4* __restrict__ h4,
                     uint2* __restrict__ hb4) {
    int idx = blockIdx.x * 256 + threadIdx.x;   // NN*32
    if (idx >= NN * 32) return;
    int cg = (idx & 31) * 4;
    float4 A = *(const float4*)&bnA[cg];
    float4 B = *(const float4*)&bnB[cg];
    uint2 tv = t4[idx];
    float t0 = h2f((ushort_t)(tv.x & 0xFFFFu)), t1 = h2f((ushort_t)(tv.x >> 16));
    float t2 = h2f((ushort_t)(tv.y & 0xFFFFu)), t3 = h2f((ushort_t)(tv.y >> 16));
    float4 nh;
    nh.x = t0 * A.x + B.x;
    nh.y = t1 * A.y + B.y;
    nh.z = t2 * A.z + B.z;
    nh.w = t3 * A.w + B.w;
    h4[idx] = nh;
    hb4[idx] = make_uint2((uint_t)f2h(nh.x) | ((uint_t)f2h(nh.y) << 16),
                          (uint_t)f2h(nh.z) | ((uint_t)f2h(nh.w) << 16));
}

// pooling: 4 blocks per graph, float4 lanes, LDS tree-reduce, 4 atomics/channel-group
__global__ void k_pool(const float4* __restrict__ h4, const int* __restrict__ goff,
                       const int* __restrict__ cnt, float* __restrict__ gsum) {
    __shared__ float4 sm[256];
    int g = blockIdx.x >> 2, sub = blockIdx.x & 3;
    int n0 = goff[g], n = cnt[g];
    int cg = threadIdx.x & 31, rl = threadIdx.x >> 5;  // rl 0..7
    float4 acc = make_float4(0.f, 0.f, 0.f, 0.f);
    for (int r = sub * 8 + rl; r < n; r += 32) {
        float4 v = h4[(size_t)(n0 + r) * 32 + cg];
        acc.x += v.x; acc.y += v.y; acc.z += v.z; acc.w += v.w;
    }
    sm[threadIdx.x] = acc; __syncthreads();
    for (int st = 128; st >= 32; st >>= 1) {
        if (threadIdx.x < st) {
            float4 o = sm[threadIdx.x + st];
            sm[threadIdx.x].x += o.x; sm[threadIdx.x].y += o.y;
            sm[threadIdx.x].z += o.z; sm[threadIdx.x].w += o.w;
        }
        __syncthreads();
    }
    if (threadIdx.x < 32) {
        float4 v = sm[threadIdx.x];
        atomicAdd(&gsum[g * HD + cg * 4 + 0], v.x);
        atomicAdd(&gsum[g * HD + cg * 4 + 1], v.y);
        atomicAdd(&gsum[g * HD + cg * 4 + 2], v.z);
        atomicAdd(&gsum[g * HD + cg * 4 + 3], v.w);
    }
}

__global__ void k_head(const float* __restrict__ gsum, const int* __restrict__ cnt,
                       const float* __restrict__ w1, const float* __restrict__ b1,
                       const float* __restrict__ w2, const float* __restrict__ b2,
                       float* __restrict__ out) {
    __shared__ float gv[HD], av[HD];
    int gid = blockIdx.x, t = threadIdx.x;
    float c = fmaxf((float)cnt[gid], 1.0f);
    gv[t] = gsum[gid * HD + t] / c;
    __syncthreads();
    float a = b1[t];
    for (int k = 0; k < HD; ++k) a += gv[k] * w1[k * HD + t];
    av[t] = fmaxf(a, 0.f);
    __syncthreads();
    if (t < NOUT) {
        float o = b2[t];
        for (int k = 0; k < HD; ++k) o += av[k] * w2[k * NOUT + t];
        out[gid * NOUT + t] = o;
    }
}

// ---------------- workspace layout ----------------
static constexpr size_t AL(size_t x) { return (x + 511) & ~(size_t)511; }
static constexpr size_t OFF_H      = 0;
static constexpr size_t OFF_HB     = OFF_H      + AL((size_t)NN * HD * 4);      // fp32 h
static constexpr size_t OFF_BUFF   = OFF_HB     + AL((size_t)NN * HD * 2);      // th fp16 (FFN2 out)
static constexpr size_t OFF_SHARE  = OFF_BUFF   + AL((size_t)NN * HD * 4);
static constexpr size_t SZ_SHARE   = AL((size_t)NN * 256 * 2);                  // aggh+z2h | f1h | epair
static constexpr size_t OFF_RW     = OFF_SHARE  + SZ_SHARE;
static constexpr size_t OFF_P0     = OFF_RW     + AL((size_t)WLK * NN * 4);
static constexpr size_t OFF_P1     = OFF_P0     + AL((size_t)NN * 4);
static constexpr size_t OFF_PD0    = OFF_P1     + AL((size_t)NN * 4);
static constexpr size_t OFF_PD1    = OFF_PD0    + AL((size_t)NN * 4);
static constexpr size_t OFF_DINV   = OFF_PD1    + AL((size_t)NN * 4);
static constexpr size_t OFF_ESRC   = OFF_DINV   + AL((size_t)NN * 4);
static constexpr size_t OFF_ROWPTR = OFF_ESRC   + AL((size_t)NE * 4);
static constexpr size_t OFF_DEG    = OFF_ROWPTR + AL((size_t)(NN + 1) * 4);
static constexpr size_t OFF_BHIST  = OFF_DEG    + AL((size_t)NN * 4);
static constexpr size_t OFF_BOFFS  = OFF_BHIST  + AL((size_t)NSCAN * 4);
static constexpr size_t OFF_BSUM   = OFF_BOFFS  + AL((size_t)NSCAN * 4);
static constexpr size_t OFF_WT1    = OFF_BSUM   + AL(512 * 4);
static constexpr size_t OFF_WT2    = OFF_WT1    + AL((size_t)5 * 16384 * 2);
static constexpr size_t OFF_WT3    = OFF_WT2    + AL((size_t)5 * 16384 * 2);
static constexpr size_t OFF_WT4    = OFF_WT3    + AL((size_t)5 * 32768 * 2);
static constexpr size_t OFF_PARTS  = OFF_WT4    + AL((size_t)5 * 32768 * 2);
static constexpr size_t OFF_PARTQ  = OFF_PARTS  + AL((size_t)128 * NBM * 4);
static constexpr size_t OFF_BNA    = OFF_PARTQ  + AL((size_t)128 * NBM * 4);
static constexpr size_t OFF_BNB    = OFF_BNA    + AL(128 * 4);
static constexpr size_t OFF_M      = OFF_BNB    + AL(128 * 4);
static constexpr size_t OFF_C1     = OFF_M      + AL((size_t)WLK * HD * 4);
static constexpr size_t OFF_CNT    = OFF_C1     + AL(HD * 4);
static constexpr size_t OFF_GOFF   = OFF_CNT    + AL(NG * 4);
static constexpr size_t OFF_GSUM   = OFF_GOFF   + AL(NG * 4);
static constexpr size_t ZERO_BYTES = (size_t)NG * HD * 4;                        // gsum only

extern "C" void kernel_launch(void* const* d_in, const int* in_sizes, int n_in,
                              void* d_out, int out_size, void* d_ws, size_t ws_size,
                              hipStream_t stream) {
    const int* eidx = (const int*)d_in[1];
    const int* row0 = eidx;
    const int* col0 = eidx + NE;
    const int* batch = (const int*)d_in[2];
    const float* emb = (const float*)d_in[3];
    const float* pe_w = (const float*)d_in[4];
    const float* pe_b = (const float*)d_in[5];
    const float* proj_w = (const float*)d_in[6];
    const float* proj_b = (const float*)d_in[7];
    const float* gin_w1 = (const float*)d_in[8];
    const float* gin_b1 = (const float*)d_in[9];
    const float* gin_w2 = (const float*)d_in[10];
    const float* gin_b2 = (const float*)d_in[11];
    const float* bn_g = (const float*)d_in[12];
    const float* bn_b = (const float*)d_in[13];
    const float* ffn_w1 = (const float*)d_in[14];
    const float* ffn_b1 = (const float*)d_in[15];
    const float* ffn_w2 = (const float*)d_in[16];
    const float* ffn_b2 = (const float*)d_in[17];
    const float* ffn_bn_g = (const float*)d_in[18];
    const float* ffn_bn_b = (const float*)d_in[19];
    const float* out_w1 = (const float*)d_in[20];
    const float* out_b1 = (const float*)d_in[21];
    const float* out_w2 = (const float*)d_in[22];
    const float* out_b2 = (const float*)d_in[23];
    float* out = (float*)d_out;

    char* ws = (char*)d_ws;
    float*    h     = (float*)(ws + OFF_H);
    ushort_t* hb    = (ushort_t*)(ws + OFF_HB);
    ushort_t* th    = (ushort_t*)(ws + OFF_BUFF);
    ushort_t* aggh  = (ushort_t*)(ws + OFF_SHARE);
    ushort_t* z2h   = (ushort_t*)(ws + OFF_SHARE + (size_t)NN * HD * 2);
    ushort_t* f1h   = (ushort_t*)(ws + OFF_SHARE);
    int2*     epair = (int2*)(ws + OFF_SHARE);
    float*    rw    = (float*)(ws + OFF_RW);
    float*    p0    = (float*)(ws + OFF_P0);
    float*    p1    = (float*)(ws + OFF_P1);
    float*    pd0   = (float*)(ws + OFF_PD0);
    float*    pd1   = (float*)(ws + OFF_PD1);
    float*    dinv  = (float*)(ws + OFF_DINV);
    int*      esrc  = (int*)(ws + OFF_ESRC);
    int*      rowptr= (int*)(ws + OFF_ROWPTR);
    int*      deg   = (int*)(ws + OFF_DEG);
    int*      bhist = (int*)(ws + OFF_BHIST);
    int*      boffs = (int*)(ws + OFF_BOFFS);
    int*      bsum  = (int*)(ws + OFF_BSUM);
    ushort_t* wt1   = (ushort_t*)(ws + OFF_WT1);
    ushort_t* wt2   = (ushort_t*)(ws + OFF_WT2);
    ushort_t* wt3   = (ushort_t*)(ws + OFF_WT3);
    ushort_t* wt4   = (ushort_t*)(ws + OFF_WT4);
    float*    partS = (float*)(ws + OFF_PARTS);
    float*    partQ = (float*)(ws + OFF_PARTQ);
    float*    bnA   = (float*)(ws + OFF_BNA);
    float*    bnB   = (float*)(ws + OFF_BNB);
    float*    M     = (float*)(ws + OFF_M);
    float*    c1    = (float*)(ws + OFF_C1);
    int*      cnt   = (int*)(ws + OFF_CNT);
    int*      goff  = (int*)(ws + OFF_GOFF);
    float*    gsum  = (float*)(ws + OFF_GSUM);

    const int NB = CDIV(NN, 256);        // 391
    const int NBV = CDIV(NN * 32, 256);  // 12500 (vec4 elementwise)

    hipMemsetAsync(ws + OFF_GSUM, 0, ZERO_BYTES, stream);

    // ---- atomic-free CSR build ----
    k_cnt<<<1, 128, 0, stream>>>(batch, cnt, goff);
    k_bhist<<<NEB, 256, 0, stream>>>(col0, bhist);
    k_gscan1<<<NSB, 256, 0, stream>>>(bhist, bsum);
    k_scan2<<<1, 512, 0, stream>>>(bsum, NSB);
    k_gscan3<<<NSB, 256, 0, stream>>>(bhist, bsum, boffs);
    k_escatter<<<NEB, 256, 0, stream>>>(row0, col0, boffs, epair);
    k_bucket<<<NBKT, 256, 0, stream>>>(epair, boffs, rowptr, deg, esrc);

    // ---- PE + projection ----
    k_init_pe<<<NB, 256, 0, stream>>>(deg, batch, cnt, dinv, p0, pd0);
    k_mc1<<<1, 128, 0, stream>>>(emb, pe_w, pe_b, proj_w, proj_b, M, c1);
    k_prepw<<<1920, 256, 0, stream>>>(gin_w1, gin_w2, ffn_w1, ffn_w2, wt1, wt2, wt3, wt4);
    for (int s = 0; s < WLK; ++s) {
        const float* pin = (s & 1) ? p1 : p0;
        const float* pdin = (s & 1) ? pd1 : pd0;
        float* pout = (s & 1) ? p0 : p1;
        float* pdout = (s & 1) ? pd0 : pd1;
        k_rw_step<<<NB, 256, 0, stream>>>(pin, pdin, rowptr, esrc, dinv,
                                          rw + (size_t)s * NN, pout, pdout);
    }
    k_proj<<<NBV, 256, 0, stream>>>(rw, M, c1, (float4*)h, (uint2*)hb);

    // ---- layers ----
    dim3 g1(NBM, 1), g2(NBM, 2);
    for (int i = 0; i < NL; ++i) {
        k_aggb<<<CDIV(NN, 4), 256, 0, stream>>>((const uint_t*)hb, rowptr, esrc, (uint_t*)aggh);
        k_gin<<<NBM, 256, 0, stream>>>(aggh, wt1 + (size_t)i * 16384, wt2 + (size_t)i * 16384,
                                       gin_b1 + i * HD, gin_b2 + i * HD, z2h, partS, partQ);
        k_bnparm<<<128, 256, 0, stream>>>(partS, partQ, bn_g + i * HD, bn_b + i * HD, bnA, bnB);
        k_bn_relu_res<<<NBV, 256, 0, stream>>>(
            (const uint2*)z2h, bnA, bnB, (float4*)h, (uint2*)hb);
        k_mgemm<128, true, true, false, false><<<g2, 256, 0, stream>>>(
            hb, wt3 + (size_t)i * 32768, ffn_b1 + i * 256, f1h, nullptr, nullptr,
            nullptr, nullptr, 256);
        k_mgemm<256, false, true, true, true><<<g1, 256, 0, stream>>>(
            f1h, wt4 + (size_t)i * 32768, ffn_b2 + i * HD, th, nullptr, h,
            partS, partQ, 128);
        k_bnparm<<<128, 256, 0, stream>>>(partS, partQ, ffn_bn_g + i * HD, ffn_bn_b + i * HD, bnA, bnB);
        k_bn<<<NBV, 256, 0, stream>>>(
            (const uint2*)th, bnA, bnB, (float4*)h, (uint2*)hb);
    }

    k_pool<<<NG * 4, 256, 0, stream>>>((const float4*)h, goff, cnt, gsum);
    k_head<<<NG, 128, 0, stream>>>(gsum, cnt, out_w1, out_b1, out_w2, out_b2, out);
}

// Round 7
// 1584.968 us; speedup vs baseline: 2.4404x; 1.0224x over previous
//
#include <hip/hip_runtime.h>
#include <math.h>

#define NN 100000
#define NE 1600000
#define NG 128
#define HD 128
#define WLK 16
#define NL 5
#define NOUT 10
#define BNEPS 1e-5f
#define CDIV(a,b) (((a)+(b)-1)/(b))

#define NBKT 782          // buckets of 128 nodes (col>>7)
#define NEB 400           // edge-blocks for bucketing
#define EPB 4000          // edges per edge-block (NEB*EPB == NE)
#define NSCAN (NBKT*NEB)  // 312800
#define NSB CDIV(NSCAN,1024)  // 306
#define NBM 782           // GEMM row-blocks (CDIV(NN,128))

typedef float f32x4 __attribute__((ext_vector_type(4)));
typedef _Float16 f16x8 __attribute__((ext_vector_type(8)));
typedef unsigned short ushort_t;
typedef unsigned int uint_t;

__device__ __forceinline__ ushort_t f2h(float x) {
    union { _Float16 h; ushort_t u; } c;
    c.h = (_Float16)x;                     // v_cvt_f16_f32, RNE
    return c.u;
}
__device__ __forceinline__ float h2f(ushort_t u) {
    union { ushort_t u; _Float16 h; } c;
    c.u = u;
    return (float)c.h;
}

// ---------------- graph counts + start offsets via binary search (batch sorted) ----------------
__global__ void k_cnt(const int* __restrict__ batch, int* __restrict__ cnt,
                      int* __restrict__ goff) {
    int g = threadIdx.x;
    if (g >= NG) return;
    int lo0 = 0, hi0 = NN;
    while (lo0 < hi0) { int m = (lo0 + hi0) >> 1; if (batch[m] < g) lo0 = m + 1; else hi0 = m; }
    int lo1 = lo0, hi1 = NN;
    while (lo1 < hi1) { int m = (lo1 + hi1) >> 1; if (batch[m] < g + 1) lo1 = m + 1; else hi1 = m; }
    cnt[g] = lo1 - lo0;
    goff[g] = lo0;
}

// ---------------- atomic-free CSR build: bucket histogram ----------------
__global__ void k_bhist(const int* __restrict__ col0, int* __restrict__ bhist) {
    __shared__ int hist[NBKT];
    for (int i = threadIdx.x; i < NBKT; i += 256) hist[i] = 0;
    __syncthreads();
    int e0 = blockIdx.x * EPB;
    for (int e = e0 + threadIdx.x; e < e0 + EPB; e += 256) atomicAdd(&hist[col0[e] >> 7], 1);
    __syncthreads();
    for (int i = threadIdx.x; i < NBKT; i += 256) bhist[i * NEB + blockIdx.x] = hist[i];
}

__global__ void k_gscan1(const int* __restrict__ in, int* __restrict__ bsum) {
    __shared__ int sm[256];
    int base = blockIdx.x * 1024 + threadIdx.x * 4;
    int s = 0;
#pragma unroll
    for (int i = 0; i < 4; ++i) { int e = base + i; if (e < NSCAN) s += in[e]; }
    sm[threadIdx.x] = s; __syncthreads();
    for (int st = 128; st > 0; st >>= 1) {
        if (threadIdx.x < st) sm[threadIdx.x] += sm[threadIdx.x + st];
        __syncthreads();
    }
    if (threadIdx.x == 0) bsum[blockIdx.x] = sm[0];
}

__global__ void k_scan2(int* __restrict__ blksum, int nblk) {
    __shared__ int sm[512];
    int t = threadIdx.x;
    int x = (t < nblk) ? blksum[t] : 0;
    sm[t] = x; __syncthreads();
    for (int s = 1; s < 512; s <<= 1) {
        int v = (t >= s) ? sm[t - s] : 0;
        __syncthreads();
        sm[t] += v;
        __syncthreads();
    }
    if (t < nblk) blksum[t] = sm[t] - x;   // exclusive
}

__global__ void k_gscan3(const int* __restrict__ in, const int* __restrict__ bsum,
                         int* __restrict__ out) {
    __shared__ int sm[256];
    int t = threadIdx.x;
    int base = blockIdx.x * 1024 + t * 4;
    int v[4]; int s = 0;
#pragma unroll
    for (int i = 0; i < 4; ++i) { int e = base + i; v[i] = (e < NSCAN) ? in[e] : 0; s += v[i]; }
    sm[t] = s; __syncthreads();
    for (int st = 1; st < 256; st <<= 1) {
        int x = (t >= st) ? sm[t - st] : 0;
        __syncthreads();
        sm[t] += x;
        __syncthreads();
    }
    int excl = sm[t] - s + bsum[blockIdx.x];
#pragma unroll
    for (int i = 0; i < 4; ++i) { int e = base + i; if (e < NSCAN) { out[e] = excl; excl += v[i]; } }
}

__global__ void k_escatter(const int* __restrict__ row0, const int* __restrict__ col0,
                           const int* __restrict__ boffs, int2* __restrict__ epair) {
    __shared__ int cur[NBKT];
    for (int i = threadIdx.x; i < NBKT; i += 256) cur[i] = boffs[i * NEB + blockIdx.x];
    __syncthreads();
    int e0 = blockIdx.x * EPB;
    for (int e = e0 + threadIdx.x; e < e0 + EPB; e += 256) {
        int c = col0[e], r = row0[e];
        int pos = atomicAdd(&cur[c >> 7], 1);
        epair[pos] = make_int2(c, r);
    }
}

__global__ void k_bucket(const int2* __restrict__ epair, const int* __restrict__ boffs,
                         int* __restrict__ rowptr, int* __restrict__ deg,
                         int* __restrict__ esrc) {
    __shared__ int cnt_[128], scn[128], cur_[128];
    int bkt = blockIdx.x, t = threadIdx.x;
    int bs = boffs[bkt * NEB];
    int be = (bkt + 1 < NBKT) ? boffs[(bkt + 1) * NEB] : NE;
    if (t < 128) cnt_[t] = 0;
    __syncthreads();
    for (int e = bs + t; e < be; e += 256) atomicAdd(&cnt_[epair[e].x & 127], 1);
    __syncthreads();
    int c = (t < 128) ? cnt_[t] : 0;
    if (t < 128) scn[t] = c;
    __syncthreads();
    for (int st = 1; st < 128; st <<= 1) {
        int x = (t >= st && t < 128) ? scn[t - st] : 0;
        __syncthreads();
        if (t < 128) scn[t] += x;
        __syncthreads();
    }
    if (t < 128) {
        int excl = scn[t] - c;
        int node = bkt * 128 + t;
        if (node < NN) { rowptr[node] = bs + excl; deg[node] = c; }
        cur_[t] = bs + excl;
    }
    if (bkt == NBKT - 1 && t == 0) rowptr[NN] = NE;
    __syncthreads();
    for (int e = bs + t; e < be; e += 256) {
        int2 p = epair[e];
        int pos = atomicAdd(&cur_[p.x & 127], 1);
        esrc[pos] = p.y;
    }
}

// ---------------- PE init ----------------
__global__ void k_init_pe(const int* __restrict__ deg, const int* __restrict__ batch,
                          const int* __restrict__ cnt, float* __restrict__ dinv,
                          float* __restrict__ p, float* __restrict__ pd) {
    int v = blockIdx.x * 256 + threadIdx.x;
    if (v >= NN) return;
    float dv = rsqrtf((float)(deg[v] + 1));   // +1: self-loop
    dinv[v] = dv;
    float pv = 1.0f / fmaxf((float)cnt[batch[v]], 1.0f);
    p[v] = pv; pd[v] = pv * dv;
}

// one RW step; unroll-4 gathers for memory-level parallelism
__global__ void k_rw_step(const float* __restrict__ pin, const float* __restrict__ pdin,
                          const int* __restrict__ rowptr, const int* __restrict__ esrc,
                          const float* __restrict__ dinv, float* __restrict__ rwslice,
                          float* __restrict__ pout, float* __restrict__ pdout) {
    int v = blockIdx.x * 256 + threadIdx.x;
    if (v >= NN) return;
    int b = rowptr[v], e = rowptr[v + 1];
    float a0 = 0.f, a1 = 0.f, a2 = 0.f, a3 = 0.f;
    int i = b;
    for (; i + 4 <= e; i += 4) {
        int s0 = esrc[i], s1 = esrc[i + 1], s2 = esrc[i + 2], s3 = esrc[i + 3];
        a0 += pdin[s0]; a1 += pdin[s1]; a2 += pdin[s2]; a3 += pdin[s3];
    }
    for (; i < e; ++i) a0 += pdin[esrc[i]];
    float s = (a0 + a1) + (a2 + a3);
    float dv = dinv[v];
    float pv = pin[v];
    float np = s * dv + pv * dv * dv;
    float nxt = 0.9f * np + 0.1f * pv;
    rwslice[v] = pv;
    pout[v] = nxt;
    pdout[v] = nxt * dv;
}

// also initializes the identity affine for layer-0 (A0=1, B0=0)
__global__ void k_mc1(const float* __restrict__ emb, const float* __restrict__ pe_w,
                      const float* __restrict__ pe_b, const float* __restrict__ proj_w,
                      const float* __restrict__ proj_b, float* __restrict__ M,
                      float* __restrict__ c1, float* __restrict__ bnA0,
                      float* __restrict__ bnB0) {
    int j = threadIdx.x;
    bnA0[j] = 1.f; bnB0[j] = 0.f;
    float c0 = proj_b[j];
    for (int d = 0; d < HD; ++d) c0 += emb[d] * proj_w[d * HD + j];
    for (int w = 0; w < WLK; ++w) c0 += pe_b[w] * proj_w[(HD + w) * HD + j];
    c1[j] = c0;
    for (int s = 0; s < WLK; ++s) {
        float m = 0.f;
        for (int w = 0; w < WLK; ++w) m += pe_w[s * WLK + w] * proj_w[(HD + w) * HD + j];
        M[s * HD + j] = m;
    }
}

// th0[v][cg..cg+3] = fp16(c1 + sum_s rw[s][v]*M[s][:])
__global__ void k_proj(const float* __restrict__ rw, const float* __restrict__ M,
                       const float* __restrict__ c1, uint2* __restrict__ th4) {
    int idx = blockIdx.x * 256 + threadIdx.x;   // NN*32
    if (idx >= NN * 32) return;
    int v = idx >> 5, cg = (idx & 31) * 4;
    float4 acc = *(const float4*)&c1[cg];
#pragma unroll
    for (int s = 0; s < WLK; ++s) {
        float r = rw[s * NN + v];
        float4 m = *(const float4*)&M[s * HD + cg];
        acc.x += r * m.x; acc.y += r * m.y; acc.z += r * m.z; acc.w += r * m.w;
    }
    th4[idx] = make_uint2((uint_t)f2h(acc.x) | ((uint_t)f2h(acc.y) << 16),
                          (uint_t)f2h(acc.z) | ((uint_t)f2h(acc.w) << 16));
}

// cast + transpose all GEMM weights to fp16 [n][k] once per call
__global__ void k_prepw(const float* __restrict__ g1, const float* __restrict__ g2,
                        const float* __restrict__ f1, const float* __restrict__ f2,
                        ushort_t* __restrict__ wt1, ushort_t* __restrict__ wt2,
                        ushort_t* __restrict__ wt3, ushort_t* __restrict__ wt4) {
    int i = blockIdx.x * 256 + threadIdx.x;   // 491520 total
    if (i < 81920) {
        int l = i >> 14, rem = i & 16383, n = rem >> 7, k = rem & 127;
        wt1[i] = f2h(g1[l * 16384 + k * 128 + n]);
    } else if (i < 163840) {
        int j = i - 81920;
        int l = j >> 14, rem = j & 16383, n = rem >> 7, k = rem & 127;
        wt2[j] = f2h(g2[l * 16384 + k * 128 + n]);
    } else if (i < 327680) {
        int j = i - 163840;
        int l = j >> 15, rem = j & 32767, n = rem >> 7, k = rem & 127;
        wt3[j] = f2h(f1[l * 32768 + k * 256 + n]);
    } else {
        int j = i - 327680;
        int l = j >> 15, rem = j & 32767, n = rem >> 8, k = rem & 255;
        wt4[j] = f2h(f2[l * 32768 + k * 128 + n]);
    }
}

// agg[v] = A0∘(t[v] + sum_j t[src_j]) + (deg+1)∘B0  (gathers raw th fp16, affine folded)
__global__ void k_aggb(const uint_t* __restrict__ th2, const int* __restrict__ rowptr,
                       const int* __restrict__ esrc, const float* __restrict__ bnA0,
                       const float* __restrict__ bnB0, uint_t* __restrict__ aggb2) {
    int wave = threadIdx.x >> 6, lane = threadIdx.x & 63;
    int v = blockIdx.x * 4 + wave;
    if (v >= NN) return;
    uint_t u = th2[(size_t)v * 64 + lane];
    float sx[8], sy[8];
#pragma unroll
    for (int k = 0; k < 8; ++k) { sx[k] = 0.f; sy[k] = 0.f; }
    sx[0] = h2f((ushort_t)(u & 0xFFFFu)); sy[0] = h2f((ushort_t)(u >> 16));
    int b = rowptr[v], e = rowptr[v + 1];
    int i = b;
    for (; i + 8 <= e; i += 8) {
        int idx[8]; uint_t x[8];
#pragma unroll
        for (int k = 0; k < 8; ++k) idx[k] = esrc[i + k];
#pragma unroll
        for (int k = 0; k < 8; ++k) x[k] = th2[(size_t)idx[k] * 64 + lane];
#pragma unroll
        for (int k = 0; k < 8; ++k) {
            sx[k] += h2f((ushort_t)(x[k] & 0xFFFFu));
            sy[k] += h2f((ushort_t)(x[k] >> 16));
        }
    }
    for (; i < e; ++i) {
        uint_t x = th2[(size_t)esrc[i] * 64 + lane];
        sx[0] += h2f((ushort_t)(x & 0xFFFFu)); sy[0] += h2f((ushort_t)(x >> 16));
    }
    float fx = ((sx[0] + sx[1]) + (sx[2] + sx[3])) + ((sx[4] + sx[5]) + (sx[6] + sx[7]));
    float fy = ((sy[0] + sy[1]) + (sy[2] + sy[3])) + ((sy[4] + sy[5]) + (sy[6] + sy[7]));
    float2 A = *(const float2*)&bnA0[lane * 2];
    float2 B = *(const float2*)&bnB0[lane * 2];
    float cf = (float)(e - b + 1);
    float ox = A.x * fx + cf * B.x;
    float oy = A.y * fy + cf * B.y;
    aggb2[(size_t)v * 64 + lane] = (uint_t)f2h(ox) | ((uint_t)f2h(oy) << 16);
}

// ---------------- fused GIN MLP: z2 = (relu(agg@W1+b1))@W2+b2, z1 stays in LDS ----------------
#define GLDK 136
__global__ __launch_bounds__(256)
void k_gin(const ushort_t* __restrict__ A, const ushort_t* __restrict__ W1T,
           const ushort_t* __restrict__ W2T, const float* __restrict__ b1,
           const float* __restrict__ b2, ushort_t* __restrict__ z2h,
           float* __restrict__ partS, float* __restrict__ partQ) {
    __shared__ ushort_t As[128 * GLDK];   // A tile, later reused for z1 (A-layout)
    __shared__ ushort_t Ws[64 * GLDK];    // weight chunk (64 output-cols x K=128)
    __shared__ float sS[128], sQ[128];
    const int tid = threadIdx.x;
    const int w = tid >> 6, l = tid & 63;
    const int lm = l & 15, lq = l >> 4;
    const int rw0 = w * 32;               // wave's 32-row strip
    const int vr0 = blockIdx.x * 128;
    if (tid < 128) { sS[tid] = 0.f; sQ[tid] = 0.f; }

    // stage A tile (K=128 all at once)
#pragma unroll
    for (int it = 0; it < 8; ++it) {
        int f = it * 256 + tid;           // 2048 16B slots
        int row = f >> 4, sl = f & 15;
        uint4 a = make_uint4(0, 0, 0, 0);
        int vr = vr0 + row;
        if (vr < NN) a = *(const uint4*)&A[(size_t)vr * HD + sl * 8];
        *(uint4*)&As[row * GLDK + sl * 8] = a;
    }

    // phase 1: z1 = A @ W1 (col chunks of 64)
    f32x4 z1a[2][2][4] = {};
    for (int c = 0; c < 2; ++c) {
        __syncthreads();
#pragma unroll
        for (int it = 0; it < 4; ++it) {
            int f = it * 256 + tid;
            int row = f >> 4, sl = f & 15;
            *(uint4*)&Ws[row * GLDK + sl * 8] =
                *(const uint4*)&W1T[(size_t)(c * 64 + row) * HD + sl * 8];
        }
        __syncthreads();
#pragma unroll
        for (int kk = 0; kk < 128; kk += 32) {
            f16x8 af[2], bf[4];
#pragma unroll
            for (int i = 0; i < 2; ++i)
                af[i] = *(const f16x8*)&As[(rw0 + i * 16 + lm) * GLDK + kk + lq * 8];
#pragma unroll
            for (int j = 0; j < 4; ++j)
                bf[j] = *(const f16x8*)&Ws[(j * 16 + lm) * GLDK + kk + lq * 8];
#pragma unroll
            for (int i = 0; i < 2; ++i)
#pragma unroll
                for (int j = 0; j < 4; ++j)
                    z1a[c][i][j] = __builtin_amdgcn_mfma_f32_16x16x32_f16(af[i], bf[j], z1a[c][i][j], 0, 0, 0);
        }
    }
    __syncthreads();                       // all A reads done; safe to overwrite with z1

    // write z1 = relu(z1a + b1) back into As in A-fragment layout
#pragma unroll
    for (int c = 0; c < 2; ++c)
#pragma unroll
        for (int j = 0; j < 4; ++j) {
            int col = c * 64 + j * 16 + lm;
            float bj = b1[col];
#pragma unroll
            for (int i = 0; i < 2; ++i)
#pragma unroll
                for (int r = 0; r < 4; ++r) {
                    int row = rw0 + i * 16 + lq * 4 + r;
                    As[row * GLDK + col] = f2h(fmaxf(z1a[c][i][j][r] + bj, 0.f));
                }
        }

    // phase 2: z2 = z1 @ W2
    f32x4 z2a[2][2][4] = {};
    for (int c2 = 0; c2 < 2; ++c2) {
        __syncthreads();
#pragma unroll
        for (int it = 0; it < 4; ++it) {
            int f = it * 256 + tid;
            int row = f >> 4, sl = f & 15;
            *(uint4*)&Ws[row * GLDK + sl * 8] =
                *(const uint4*)&W2T[(size_t)(c2 * 64 + row) * HD + sl * 8];
        }
        __syncthreads();
#pragma unroll
        for (int kk = 0; kk < 128; kk += 32) {
            f16x8 af[2], bf[4];
#pragma unroll
            for (int i = 0; i < 2; ++i)
                af[i] = *(const f16x8*)&As[(rw0 + i * 16 + lm) * GLDK + kk + lq * 8];
#pragma unroll
            for (int j = 0; j < 4; ++j)
                bf[j] = *(const f16x8*)&Ws[(j * 16 + lm) * GLDK + kk + lq * 8];
#pragma unroll
            for (int i = 0; i < 2; ++i)
#pragma unroll
                for (int j = 0; j < 4; ++j)
                    z2a[c2][i][j] = __builtin_amdgcn_mfma_f32_16x16x32_f16(af[i], bf[j], z2a[c2][i][j], 0, 0, 0);
        }
    }

    // epilogue: bias + fp16 store + BN partial stats
    float ls[2][4] = {}, lsq[2][4] = {};
#pragma unroll
    for (int c2 = 0; c2 < 2; ++c2)
#pragma unroll
        for (int j = 0; j < 4; ++j) {
            int col = c2 * 64 + j * 16 + lm;
            float bj = b2[col];
#pragma unroll
            for (int i = 0; i < 2; ++i)
#pragma unroll
                for (int r = 0; r < 4; ++r) {
                    int vr = vr0 + rw0 + i * 16 + lq * 4 + r;
                    if (vr < NN) {
                        float x = z2a[c2][i][j][r] + bj;
                        ls[c2][j] += x; lsq[c2][j] += x * x;
                        z2h[(size_t)vr * HD + col] = f2h(x);
                    }
                }
        }
#pragma unroll
    for (int c2 = 0; c2 < 2; ++c2)
#pragma unroll
        for (int j = 0; j < 4; ++j) {
            atomicAdd(&sS[c2 * 64 + j * 16 + lm], ls[c2][j]);
            atomicAdd(&sQ[c2 * 64 + j * 16 + lm], lsq[c2][j]);
        }
    __syncthreads();
    if (tid < 128) {
        partS[(size_t)tid * NBM + blockIdx.x] = sS[tid];
        partQ[(size_t)tid * NBM + blockIdx.x] = sQ[tid];
    }
}

// ---------------- fused FFN1: h_mid = (A0∘t+B0) + relu(A1∘z2+B1), write h_mid fp32,
// then f1 = relu(h_mid @ W3 + b3)  (128 rows x 256 cols, 4 col-chunks) ----------------
__global__ __launch_bounds__(256)
void k_ffn1(const ushort_t* __restrict__ th, const ushort_t* __restrict__ z2h,
            const ushort_t* __restrict__ W3T, const float* __restrict__ b3,
            const float* __restrict__ bnA0, const float* __restrict__ bnB0,
            const float* __restrict__ bnA1, const float* __restrict__ bnB1,
            float* __restrict__ hmid, ushort_t* __restrict__ f1h) {
    __shared__ ushort_t As[128 * GLDK];
    __shared__ ushort_t Ws[64 * GLDK];
    __shared__ float sA0[128], sB0[128], sA1[128], sB1[128];
    const int tid = threadIdx.x;
    const int w = tid >> 6, l = tid & 63;
    const int lm = l & 15, lq = l >> 4;
    const int rw0 = w * 32;
    const int vr0 = blockIdx.x * 128;

    if (tid < 128) {
        sA0[tid] = bnA0[tid]; sB0[tid] = bnB0[tid];
        sA1[tid] = bnA1[tid]; sB1[tid] = bnB1[tid];
    }
    __syncthreads();

    // stage: compute h_mid on the fly, write fp32 h_mid + fp16 LDS A-tile
#pragma unroll
    for (int it = 0; it < 8; ++it) {
        int f = it * 256 + tid;           // 2048 16B slots
        int row = f >> 4, sl = f & 15;
        int vr = vr0 + row;
        uint4 o = make_uint4(0, 0, 0, 0);
        if (vr < NN) {
            uint4 tv = *(const uint4*)&th[(size_t)vr * HD + sl * 8];
            uint4 zv = *(const uint4*)&z2h[(size_t)vr * HD + sl * 8];
            uint_t tu[4] = {tv.x, tv.y, tv.z, tv.w};
            uint_t zu[4] = {zv.x, zv.y, zv.z, zv.w};
            float hm[8];
            uint_t ou[4];
#pragma unroll
            for (int m = 0; m < 4; ++m) {
                int ch0 = sl * 8 + m * 2;
                float t0 = h2f((ushort_t)(tu[m] & 0xFFFFu));
                float t1 = h2f((ushort_t)(tu[m] >> 16));
                float z0 = h2f((ushort_t)(zu[m] & 0xFFFFu));
                float z1 = h2f((ushort_t)(zu[m] >> 16));
                float h0 = sA0[ch0] * t0 + sB0[ch0] + fmaxf(sA1[ch0] * z0 + sB1[ch0], 0.f);
                float h1 = sA0[ch0 + 1] * t1 + sB0[ch0 + 1] + fmaxf(sA1[ch0 + 1] * z1 + sB1[ch0 + 1], 0.f);
                hm[m * 2] = h0; hm[m * 2 + 1] = h1;
                ou[m] = (uint_t)f2h(h0) | ((uint_t)f2h(h1) << 16);
            }
            o = make_uint4(ou[0], ou[1], ou[2], ou[3]);
            *(float4*)&hmid[(size_t)vr * HD + sl * 8] = make_float4(hm[0], hm[1], hm[2], hm[3]);
            *(float4*)&hmid[(size_t)vr * HD + sl * 8 + 4] = make_float4(hm[4], hm[5], hm[6], hm[7]);
        }
        *(uint4*)&As[row * GLDK + sl * 8] = o;
    }

    // GEMM: 4 chunks of 64 output cols
    for (int c = 0; c < 4; ++c) {
        __syncthreads();
#pragma unroll
        for (int it = 0; it < 4; ++it) {
            int f = it * 256 + tid;
            int row = f >> 4, sl = f & 15;
            *(uint4*)&Ws[row * GLDK + sl * 8] =
                *(const uint4*)&W3T[(size_t)(c * 64 + row) * HD + sl * 8];
        }
        __syncthreads();
        f32x4 acc[2][4] = {};
#pragma unroll
        for (int kk = 0; kk < 128; kk += 32) {
            f16x8 af[2], bf[4];
#pragma unroll
            for (int i = 0; i < 2; ++i)
                af[i] = *(const f16x8*)&As[(rw0 + i * 16 + lm) * GLDK + kk + lq * 8];
#pragma unroll
            for (int j = 0; j < 4; ++j)
                bf[j] = *(const f16x8*)&Ws[(j * 16 + lm) * GLDK + kk + lq * 8];
#pragma unroll
            for (int i = 0; i < 2; ++i)
#pragma unroll
                for (int j = 0; j < 4; ++j)
                    acc[i][j] = __builtin_amdgcn_mfma_f32_16x16x32_f16(af[i], bf[j], acc[i][j], 0, 0, 0);
        }
#pragma unroll
        for (int j = 0; j < 4; ++j) {
            int col = c * 64 + j * 16 + lm;
            float bj = b3[col];
#pragma unroll
            for (int i = 0; i < 2; ++i)
#pragma unroll
                for (int r = 0; r < 4; ++r) {
                    int vr = vr0 + rw0 + i * 16 + lq * 4 + r;
                    if (vr < NN)
                        f1h[(size_t)vr * 256 + col] = f2h(fmaxf(acc[i][j][r] + bj, 0.f));
                }
        }
    }
}

// ---------------- fp16 MFMA GEMM (used for FFN2): 128x128 tile ----------------
template <int K, bool RELU, bool OUTH16, bool ADDRES, bool DOSTATS>
__global__ __launch_bounds__(256, 2)
void k_mgemm(const ushort_t* __restrict__ A, const ushort_t* __restrict__ WT,
             const float* __restrict__ bias, ushort_t* __restrict__ Ch,
             float* __restrict__ Cf, const float* __restrict__ res,
             float* __restrict__ partS, float* __restrict__ partQ, int ncols) {
    constexpr int LDK = 72;
    __shared__ ushort_t As[128 * LDK];
    __shared__ ushort_t Ws[128 * LDK];
    __shared__ float sS[128], sQ[128];
    const int tid = threadIdx.x;
    const int w = tid >> 6, l = tid & 63;
    const int lm = l & 15, lq = l >> 4;
    const int rb = (w >> 1) * 64, cbw = (w & 1) * 64;
    const int vr0 = blockIdx.x * 128;
    const int cb = blockIdx.y * 128;
    f32x4 acc[4][4] = {};

    for (int kt = 0; kt < K / 64; ++kt) {
        __syncthreads();
#pragma unroll
        for (int it = 0; it < 4; ++it) {
            int f = it * 256 + tid;
            int row = f >> 3, sl = f & 7;
            uint4 a = make_uint4(0, 0, 0, 0);
            int vr = vr0 + row;
            if (vr < NN) a = *(const uint4*)&A[(size_t)vr * K + kt * 64 + sl * 8];
            *(uint4*)&As[row * LDK + sl * 8] = a;
            uint4 wv = *(const uint4*)&WT[(size_t)(cb + row) * K + kt * 64 + sl * 8];
            *(uint4*)&Ws[row * LDK + sl * 8] = wv;
        }
        __syncthreads();
#pragma unroll
        for (int kk = 0; kk < 64; kk += 32) {
            f16x8 af[4], bf[4];
#pragma unroll
            for (int i = 0; i < 4; ++i)
                af[i] = *(const f16x8*)&As[(rb + i * 16 + lm) * LDK + kk + lq * 8];
#pragma unroll
            for (int j = 0; j < 4; ++j)
                bf[j] = *(const f16x8*)&Ws[(cbw + j * 16 + lm) * LDK + kk + lq * 8];
#pragma unroll
            for (int i = 0; i < 4; ++i)
#pragma unroll
                for (int j = 0; j < 4; ++j)
                    acc[i][j] = __builtin_amdgcn_mfma_f32_16x16x32_f16(af[i], bf[j], acc[i][j], 0, 0, 0);
        }
    }

    float bcol[4];
#pragma unroll
    for (int j = 0; j < 4; ++j) bcol[j] = bias[cb + cbw + j * 16 + lm];
    if (DOSTATS && tid < 128) { sS[tid] = 0.f; sQ[tid] = 0.f; }
    __syncthreads();
    float ls[4] = {0, 0, 0, 0}, lsq[4] = {0, 0, 0, 0};
#pragma unroll
    for (int i = 0; i < 4; ++i) {
#pragma unroll
        for (int r = 0; r < 4; ++r) {
            int vr = vr0 + rb + i * 16 + lq * 4 + r;
            if (vr < NN) {
#pragma unroll
                for (int j = 0; j < 4; ++j) {
                    float x = acc[i][j][r] + bcol[j];
                    if (RELU) x = fmaxf(x, 0.f);
                    int c = cb + cbw + j * 16 + lm;
                    if (ADDRES) x += res[(size_t)vr * ncols + c];
                    if (DOSTATS) { ls[j] += x; lsq[j] += x * x; }
                    if (OUTH16) Ch[(size_t)vr * ncols + c] = f2h(x);
                    else        Cf[(size_t)vr * ncols + c] = x;
                }
            }
        }
    }
    if (DOSTATS) {
#pragma unroll
        for (int j = 0; j < 4; ++j) {
            atomicAdd(&sS[cbw + j * 16 + lm], ls[j]);
            atomicAdd(&sQ[cbw + j * 16 + lm], lsq[j]);
        }
        __syncthreads();
        if (tid < 128) {
            partS[(size_t)(cb + tid) * NBM + blockIdx.x] = sS[tid];
            partQ[(size_t)(cb + tid) * NBM + blockIdx.x] = sQ[tid];
        }
    }
}

// reduce per-block partial sums -> per-channel BN scale/shift: y = x*bnA[c] + bnB[c]
__global__ void k_bnparm(const float* __restrict__ partS, const float* __restrict__ partQ,
                         const float* __restrict__ g, const float* __restrict__ b,
                         float* __restrict__ bnA, float* __restrict__ bnB) {
    __shared__ float smS[256], smQ[256];
    int c = blockIdx.x, t = threadIdx.x;
    float s = 0.f, q = 0.f;
    for (int i = t; i < NBM; i += 256) {
        s += partS[(size_t)c * NBM + i];
        q += partQ[(size_t)c * NBM + i];
    }
    smS[t] = s; smQ[t] = q; __syncthreads();
    for (int st = 128; st > 0; st >>= 1) {
        if (t < st) { smS[t] += smS[t + st]; smQ[t] += smQ[t + st]; }
        __syncthreads();
    }
    if (t == 0) {
        float mu = smS[0] * (1.0f / NN);
        float var = smQ[0] * (1.0f / NN) - mu * mu;
        float inv = rsqrtf(var + BNEPS);
        float a = g[c] * inv;
        bnA[c] = a;
        bnB[c] = b[c] - mu * a;
    }
}

// pooling over raw th: gsum[g] = sum_v t[v]; affine applied in k_head
__global__ void k_pool(const uint2* __restrict__ th4, const int* __restrict__ goff,
                       const int* __restrict__ cnt, float* __restrict__ gsum) {
    __shared__ float4 sm[256];
    int g = blockIdx.x >> 2, sub = blockIdx.x & 3;
    int n0 = goff[g], n = cnt[g];
    int cg = threadIdx.x & 31, rl = threadIdx.x >> 5;  // rl 0..7
    float4 acc = make_float4(0.f, 0.f, 0.f, 0.f);
    for (int r = sub * 8 + rl; r < n; r += 32) {
        uint2 v = th4[(size_t)(n0 + r) * 32 + cg];
        acc.x += h2f((ushort_t)(v.x & 0xFFFFu));
        acc.y += h2f((ushort_t)(v.x >> 16));
        acc.z += h2f((ushort_t)(v.y & 0xFFFFu));
        acc.w += h2f((ushort_t)(v.y >> 16));
    }
    sm[threadIdx.x] = acc; __syncthreads();
    for (int st = 128; st >= 32; st >>= 1) {
        if (threadIdx.x < st) {
            float4 o = sm[threadIdx.x + st];
            sm[threadIdx.x].x += o.x; sm[threadIdx.x].y += o.y;
            sm[threadIdx.x].z += o.z; sm[threadIdx.x].w += o.w;
        }
        __syncthreads();
    }
    if (threadIdx.x < 32) {
        float4 v = sm[threadIdx.x];
        atomicAdd(&gsum[g * HD + cg * 4 + 0], v.x);
        atomicAdd(&gsum[g * HD + cg * 4 + 1], v.y);
        atomicAdd(&gsum[g * HD + cg * 4 + 2], v.z);
        atomicAdd(&gsum[g * HD + cg * 4 + 3], v.w);
    }
}

__global__ void k_head(const float* __restrict__ gsum, const int* __restrict__ cnt,
                       const float* __restrict__ bnA0, const float* __restrict__ bnB0,
                       const float* __restrict__ w1, const float* __restrict__ b1,
                       const float* __restrict__ w2, const float* __restrict__ b2,
                       float* __restrict__ out) {
    __shared__ float gv[HD], av[HD];
    int gid = blockIdx.x, t = threadIdx.x;
    float c = fmaxf((float)cnt[gid], 1.0f);
    gv[t] = bnA0[t] * (gsum[gid * HD + t] / c) + bnB0[t];   // mean then affine
    __syncthreads();
    float a = b1[t];
    for (int k = 0; k < HD; ++k) a += gv[k] * w1[k * HD + t];
    av[t] = fmaxf(a, 0.f);
    __syncthreads();
    if (t < NOUT) {
        float o = b2[t];
        for (int k = 0; k < HD; ++k) o += av[k] * w2[k * NOUT + t];
        out[gid * NOUT + t] = o;
    }
}

// ---------------- workspace layout ----------------
// NOTE: z2h has its OWN region (OFF_Z2). In round 6 it aliased the tail of the
// share arena while k_ffn1 wrote f1h into the same arena concurrently with
// reading z2h -> inter-block race -> nondeterministic output (tripwire).
static constexpr size_t AL(size_t x) { return (x + 511) & ~(size_t)511; }
static constexpr size_t OFF_HMID   = 0;
static constexpr size_t OFF_TH     = OFF_HMID   + AL((size_t)NN * HD * 4);      // fp16 t (BN input)
static constexpr size_t OFF_SHARE  = OFF_TH     + AL((size_t)NN * HD * 2);
static constexpr size_t SZ_SHARE   = AL((size_t)NN * 256 * 2);                  // aggh | f1h | epair
static constexpr size_t OFF_Z2     = OFF_SHARE  + SZ_SHARE;                     // z2h fp16 (dedicated)
static constexpr size_t OFF_RW     = OFF_Z2     + AL((size_t)NN * HD * 2);
static constexpr size_t OFF_P0     = OFF_RW     + AL((size_t)WLK * NN * 4);
static constexpr size_t OFF_P1     = OFF_P0     + AL((size_t)NN * 4);
static constexpr size_t OFF_PD0    = OFF_P1     + AL((size_t)NN * 4);
static constexpr size_t OFF_PD1    = OFF_PD0    + AL((size_t)NN * 4);
static constexpr size_t OFF_DINV   = OFF_PD1    + AL((size_t)NN * 4);
static constexpr size_t OFF_ESRC   = OFF_DINV   + AL((size_t)NN * 4);
static constexpr size_t OFF_ROWPTR = OFF_ESRC   + AL((size_t)NE * 4);
static constexpr size_t OFF_DEG    = OFF_ROWPTR + AL((size_t)(NN + 1) * 4);
static constexpr size_t OFF_BHIST  = OFF_DEG    + AL((size_t)NN * 4);
static constexpr size_t OFF_BOFFS  = OFF_BHIST  + AL((size_t)NSCAN * 4);
static constexpr size_t OFF_BSUM   = OFF_BOFFS  + AL((size_t)NSCAN * 4);
static constexpr size_t OFF_WT1    = OFF_BSUM   + AL(512 * 4);
static constexpr size_t OFF_WT2    = OFF_WT1    + AL((size_t)5 * 16384 * 2);
static constexpr size_t OFF_WT3    = OFF_WT2    + AL((size_t)5 * 16384 * 2);
static constexpr size_t OFF_WT4    = OFF_WT3    + AL((size_t)5 * 32768 * 2);
static constexpr size_t OFF_PARTS  = OFF_WT4    + AL((size_t)5 * 32768 * 2);
static constexpr size_t OFF_PARTQ  = OFF_PARTS  + AL((size_t)128 * NBM * 4);
static constexpr size_t OFF_BNA0   = OFF_PARTQ  + AL((size_t)128 * NBM * 4);
static constexpr size_t OFF_BNB0   = OFF_BNA0   + AL(128 * 4);
static constexpr size_t OFF_BNA1   = OFF_BNB0   + AL(128 * 4);
static constexpr size_t OFF_BNB1   = OFF_BNA1   + AL(128 * 4);
static constexpr size_t OFF_M      = OFF_BNB1   + AL(128 * 4);
static constexpr size_t OFF_C1     = OFF_M      + AL((size_t)WLK * HD * 4);
static constexpr size_t OFF_CNT    = OFF_C1     + AL(HD * 4);
static constexpr size_t OFF_GOFF   = OFF_CNT    + AL(NG * 4);
static constexpr size_t OFF_GSUM   = OFF_GOFF   + AL(NG * 4);
static constexpr size_t ZERO_BYTES = (size_t)NG * HD * 4;                        // gsum only

extern "C" void kernel_launch(void* const* d_in, const int* in_sizes, int n_in,
                              void* d_out, int out_size, void* d_ws, size_t ws_size,
                              hipStream_t stream) {
    const int* eidx = (const int*)d_in[1];
    const int* row0 = eidx;
    const int* col0 = eidx + NE;
    const int* batch = (const int*)d_in[2];
    const float* emb = (const float*)d_in[3];
    const float* pe_w = (const float*)d_in[4];
    const float* pe_b = (const float*)d_in[5];
    const float* proj_w = (const float*)d_in[6];
    const float* proj_b = (const float*)d_in[7];
    const float* gin_w1 = (const float*)d_in[8];
    const float* gin_b1 = (const float*)d_in[9];
    const float* gin_w2 = (const float*)d_in[10];
    const float* gin_b2 = (const float*)d_in[11];
    const float* bn_g = (const float*)d_in[12];
    const float* bn_b = (const float*)d_in[13];
    const float* ffn_w1 = (const float*)d_in[14];
    const float* ffn_b1 = (const float*)d_in[15];
    const float* ffn_w2 = (const float*)d_in[16];
    const float* ffn_b2 = (const float*)d_in[17];
    const float* ffn_bn_g = (const float*)d_in[18];
    const float* ffn_bn_b = (const float*)d_in[19];
    const float* out_w1 = (const float*)d_in[20];
    const float* out_b1 = (const float*)d_in[21];
    const float* out_w2 = (const float*)d_in[22];
    const float* out_b2 = (const float*)d_in[23];
    float* out = (float*)d_out;

    char* ws = (char*)d_ws;
    float*    hmid  = (float*)(ws + OFF_HMID);
    ushort_t* th    = (ushort_t*)(ws + OFF_TH);
    ushort_t* aggh  = (ushort_t*)(ws + OFF_SHARE);
    ushort_t* f1h   = (ushort_t*)(ws + OFF_SHARE);    // aliases aggh (dead after k_gin)
    ushort_t* z2h   = (ushort_t*)(ws + OFF_Z2);       // dedicated — no overlap with f1h
    int2*     epair = (int2*)(ws + OFF_SHARE);
    float*    rw    = (float*)(ws + OFF_RW);
    float*    p0    = (float*)(ws + OFF_P0);
    float*    p1    = (float*)(ws + OFF_P1);
    float*    pd0   = (float*)(ws + OFF_PD0);
    float*    pd1   = (float*)(ws + OFF_PD1);
    float*    dinv  = (float*)(ws + OFF_DINV);
    int*      esrc  = (int*)(ws + OFF_ESRC);
    int*      rowptr= (int*)(ws + OFF_ROWPTR);
    int*      deg   = (int*)(ws + OFF_DEG);
    int*      bhist = (int*)(ws + OFF_BHIST);
    int*      boffs = (int*)(ws + OFF_BOFFS);
    int*      bsum  = (int*)(ws + OFF_BSUM);
    ushort_t* wt1   = (ushort_t*)(ws + OFF_WT1);
    ushort_t* wt2   = (ushort_t*)(ws + OFF_WT2);
    ushort_t* wt3   = (ushort_t*)(ws + OFF_WT3);
    ushort_t* wt4   = (ushort_t*)(ws + OFF_WT4);
    float*    partS = (float*)(ws + OFF_PARTS);
    float*    partQ = (float*)(ws + OFF_PARTQ);
    float*    bnA0  = (float*)(ws + OFF_BNA0);
    float*    bnB0  = (float*)(ws + OFF_BNB0);
    float*    bnA1  = (float*)(ws + OFF_BNA1);
    float*    bnB1  = (float*)(ws + OFF_BNB1);
    float*    M     = (float*)(ws + OFF_M);
    float*    c1    = (float*)(ws + OFF_C1);
    int*      cnt   = (int*)(ws + OFF_CNT);
    int*      goff  = (int*)(ws + OFF_GOFF);
    float*    gsum  = (float*)(ws + OFF_GSUM);

    const int NB = CDIV(NN, 256);        // 391
    const int NBV = CDIV(NN * 32, 256);  // 12500

    hipMemsetAsync(ws + OFF_GSUM, 0, ZERO_BYTES, stream);

    // ---- atomic-free CSR build ----
    k_cnt<<<1, 128, 0, stream>>>(batch, cnt, goff);
    k_bhist<<<NEB, 256, 0, stream>>>(col0, bhist);
    k_gscan1<<<NSB, 256, 0, stream>>>(bhist, bsum);
    k_scan2<<<1, 512, 0, stream>>>(bsum, NSB);
    k_gscan3<<<NSB, 256, 0, stream>>>(bhist, bsum, boffs);
    k_escatter<<<NEB, 256, 0, stream>>>(row0, col0, boffs, epair);
    k_bucket<<<NBKT, 256, 0, stream>>>(epair, boffs, rowptr, deg, esrc);

    // ---- PE + projection ----
    k_init_pe<<<NB, 256, 0, stream>>>(deg, batch, cnt, dinv, p0, pd0);
    k_mc1<<<1, 128, 0, stream>>>(emb, pe_w, pe_b, proj_w, proj_b, M, c1, bnA0, bnB0);
    k_prepw<<<1920, 256, 0, stream>>>(gin_w1, gin_w2, ffn_w1, ffn_w2, wt1, wt2, wt3, wt4);
    for (int s = 0; s < WLK; ++s) {
        const float* pin = (s & 1) ? p1 : p0;
        const float* pdin = (s & 1) ? pd1 : pd0;
        float* pout = (s & 1) ? p0 : p1;
        float* pdout = (s & 1) ? pd0 : pd1;
        k_rw_step<<<NB, 256, 0, stream>>>(pin, pdin, rowptr, esrc, dinv,
                                          rw + (size_t)s * NN, pout, pdout);
    }
    k_proj<<<NBV, 256, 0, stream>>>(rw, M, c1, (uint2*)th);

    // ---- layers (BN folded into gather/staging via per-channel affine) ----
    dim3 g1(NBM, 1);
    for (int i = 0; i < NL; ++i) {
        k_aggb<<<CDIV(NN, 4), 256, 0, stream>>>((const uint_t*)th, rowptr, esrc,
                                                bnA0, bnB0, (uint_t*)aggh);
        k_gin<<<NBM, 256, 0, stream>>>(aggh, wt1 + (size_t)i * 16384, wt2 + (size_t)i * 16384,
                                       gin_b1 + i * HD, gin_b2 + i * HD, z2h, partS, partQ);
        k_bnparm<<<128, 256, 0, stream>>>(partS, partQ, bn_g + i * HD, bn_b + i * HD, bnA1, bnB1);
        k_ffn1<<<NBM, 256, 0, stream>>>(th, z2h, wt3 + (size_t)i * 32768, ffn_b1 + i * 256,
                                        bnA0, bnB0, bnA1, bnB1, hmid, f1h);
        k_mgemm<256, false, true, true, true><<<g1, 256, 0, stream>>>(
            f1h, wt4 + (size_t)i * 32768, ffn_b2 + i * HD, th, nullptr, hmid,
            partS, partQ, 128);
        k_bnparm<<<128, 256, 0, stream>>>(partS, partQ, ffn_bn_g + i * HD, ffn_bn_b + i * HD,
                                          bnA0, bnB0);
    }

    k_pool<<<NG * 4, 256, 0, stream>>>((const uint2*)th, goff, cnt, gsum);
    k_head<<<NG, 128, 0, stream>>>(gsum, cnt, bnA0, bnB0, out_w1, out_b1, out_w2, out_b2, out);
}